// Round 11
// baseline (204.004 us; speedup 1.0000x reference)
//
#include <hip/hip_runtime.h>

#define L_SEQ 2048
#define NB    2
#define DMOD  1024
#define DIN   2048
#define NST   16
#define NROWS (NB*L_SEQ)   // 4096
#define CL    64
#define NC    (L_SEQ/CL)   // 32

typedef unsigned short u16;
typedef _Float16 half8 __attribute__((ext_vector_type(8)));
typedef float f32x4 __attribute__((ext_vector_type(4)));
typedef short short8 __attribute__((ext_vector_type(8)));

__device__ __forceinline__ float siluf(float v){ return v / (1.f + __expf(-v)); }
__device__ __forceinline__ u16 f2h_bits(float v){ _Float16 h = (_Float16)v; return __builtin_bit_cast(u16, h); }
__device__ __forceinline__ float h2f(u16 v){ return (float)__builtin_bit_cast(_Float16, v); }
__device__ __forceinline__ float fexp2(float x){
#if __has_builtin(__builtin_amdgcn_exp2f)
    return __builtin_amdgcn_exp2f(x);
#else
    return __expf(x * 0.69314718056f);
#endif
}

// async global->LDS, 16B per lane; lds base wave-uniform; dest = base + lane*16
__device__ __forceinline__ void gload16(const u16* g, u16* l)
{
    __builtin_amdgcn_global_load_lds(
        (const __attribute__((address_space(1))) void*)g,
        (__attribute__((address_space(3))) void*)l,
        16, 0, 0);
}

#define BARRIER() do { asm volatile("" ::: "memory"); __builtin_amdgcn_s_barrier(); asm volatile("" ::: "memory"); } while (0)
#define VMCNT4()  asm volatile("s_waitcnt vmcnt(4)" ::: "memory")
#define VMCNT0()  asm volatile("s_waitcnt vmcnt(0)" ::: "memory")

// ---------------- fused input preprocessing ----------------
__global__ __launch_bounds__(256)
void prep_inputs(const float* __restrict__ x, const float* __restrict__ W_in,
                 const float* __restrict__ W_out, const float* __restrict__ Wx,
                 u16* __restrict__ x16, u16* __restrict__ Bt1,
                 u16* __restrict__ Bt3, u16* __restrict__ WxT16)
{
    __shared__ float s[64][65];
    const int bid = blockIdx.x, tid = threadIdx.x;
    if (bid < 4096) {
        int i = bid * 256 + tid;                   // over NROWS*DMOD/4
        float4 v = ((const float4*)x)[i];
        ushort4 o;
        o.x = f2h_bits(v.x); o.y = f2h_bits(v.y); o.z = f2h_bits(v.z); o.w = f2h_bits(v.w);
        *(ushort4*)&x16[(size_t)i * 4] = o;
    } else if (bid < 5632) {
        const float* in; u16* outT; int R, C, rblk, cblk;
        if (bid < 5120) { int b = bid - 4096; in = W_in;  outT = Bt1; R = 1024; C = 4096; cblk = b & 63; rblk = b >> 6; }
        else            { int b = bid - 5120; in = W_out; outT = Bt3; R = 2048; C = 1024; cblk = b & 15; rblk = b >> 4; }
        int r0 = rblk * 64, c0 = cblk * 64;
        int tc = tid & 63, ty = tid >> 6;
        #pragma unroll
        for (int j = 0; j < 16; j++) {
            int r = ty + j * 4;
            s[r][tc] = in[(size_t)(r0 + r) * C + c0 + tc];
        }
        __syncthreads();
        #pragma unroll
        for (int j = 0; j < 16; j++) {
            int nn = ty + j * 4;
            outT[(size_t)(c0 + nn) * R + r0 + tc] = f2h_bits(s[tc][nn]);
        }
    } else {
        int idx = (bid - 5632) * 256 + tid;        // 48*2048
        int n = idx >> 11, k = idx & 2047;
        float v = (n < 33) ? Wx[k * 33 + n] : 0.f;
        WxT16[idx] = f2h_bits(v);
    }
}

// ---------------- gemm97: 128x128 tile, BK=32, 4 waves, 3-buffer LDS, counted vmcnt ----
// m97-style high-TLP design: 48KB LDS -> 3 blocks/CU (12 waves), 2-tile-ahead prefetch,
// ONE barrier per K-tile, vmcnt(4) in steady state (vmcnt(0) only at final tile).
// Swizzle: LDS[row][s] = G[row][s ^ (row&3) ^ ((row>>2)&3)] via pre-swizzled source unit.
// EPI==1: split N at half: col<half -> C0h (u16) ; else C1h = silu (u16)
// EPI==2: u16 partial at C0h[(z*M + row)*N + col]
template<int EPI>
__global__ __launch_bounds__(256, 3)
void gemm97(const u16* __restrict__ A, const u16* __restrict__ Bt,
            void* __restrict__ C0v, void* __restrict__ C1v,
            int M, int N, int KLEN, int lda, int ldb)
{
    __shared__ __align__(16) u16 As[3 * 128 * 32];   // 24 KB (3 bufs x 8KB)
    __shared__ __align__(16) u16 Bs[3 * 128 * 32];   // 24 KB
    const int tid  = threadIdx.x;
    const int lane = tid & 63;
    const int wid  = tid >> 6;                 // 0..3
    const int wm   = wid >> 1, wn = wid & 1;
    const int bm = blockIdx.y * 128, bn = blockIdx.x * 128;
    const int kBase = blockIdx.z * KLEN;

    // staging: call c covers rows c*16 + (l>>2); lane unit (l&3); pre-swizzled source unit
    const int srow = lane >> 2;                          // 0..15
    const int g    = (lane & 3) ^ (srow & 3) ^ (lane >> 4);  // global 16B-unit
    const u16* Ag = A  + (size_t)(bm + srow) * lda + kBase + g * 8;
    const u16* Bg = Bt + (size_t)(bn + srow) * ldb + kBase + g * 8;
    const int c0 = wid * 2, c1 = wid * 2 + 1;            // this wave's two calls per operand

    // fragment read offsets (elements within one 8KB buf)
    const int fr  = lane & 15;
    const int sl0 = ((lane >> 4) ^ (fr & 3) ^ (fr >> 2)) & 3;
    int aOff[4], bOff[4];
    #pragma unroll
    for (int mi = 0; mi < 4; mi++) aOff[mi] = (wm * 64 + mi * 16 + fr) * 32 + sl0 * 8;
    #pragma unroll
    for (int ni = 0; ni < 4; ni++) bOff[ni] = (wn * 64 + ni * 16 + fr) * 32 + sl0 * 8;

    f32x4 acc[4][4];
    #pragma unroll
    for (int i = 0; i < 4; i++)
        #pragma unroll
        for (int j = 0; j < 4; j++)
            acc[i][j] = (f32x4){0.f, 0.f, 0.f, 0.f};

    auto STAGE = [&](int t, int buf) {                   // 4 gloads/wave
        const int kc = t * 32;
        u16* Ad = &As[buf * 4096];
        u16* Bd = &Bs[buf * 4096];
        gload16(Ag + (size_t)(c0 * 16) * lda + kc, Ad + c0 * 512);
        gload16(Ag + (size_t)(c1 * 16) * lda + kc, Ad + c1 * 512);
        gload16(Bg + (size_t)(c0 * 16) * ldb + kc, Bd + c0 * 512);
        gload16(Bg + (size_t)(c1 * 16) * ldb + kc, Bd + c1 * 512);
    };

    const int NT = KLEN >> 5;                            // K/32 (>= 3 for all shapes)
    STAGE(0, 0);
    STAGE(1, 1);

    int buf = 0;
    for (int t = 0; t < NT; ++t) {
        if (t + 1 < NT) VMCNT4(); else VMCNT0();         // tile t's 4 loads complete
        BARRIER();                                        // all waves' t-loads visible
        const int bO = buf * 4096;
        if (t + 2 < NT) {
            int nb = buf + 2; if (nb >= 3) nb -= 3;
            STAGE(t + 2, nb);
        }
        half8 af[4], bf[4];
        #pragma unroll
        for (int mi = 0; mi < 4; mi++) af[mi] = *(const half8*)&As[bO + aOff[mi]];
        #pragma unroll
        for (int ni = 0; ni < 4; ni++) bf[ni] = *(const half8*)&Bs[bO + bOff[ni]];
        #pragma unroll
        for (int mi = 0; mi < 4; mi++)
            #pragma unroll
            for (int ni = 0; ni < 4; ni++)
                acc[mi][ni] = __builtin_amdgcn_mfma_f32_16x16x32_f16(af[mi], bf[ni], acc[mi][ni], 0, 0, 0);
        buf = (buf == 2) ? 0 : buf + 1;
    }

    const int cr = (lane >> 4) * 4;
    const int cc = lane & 15;
    #pragma unroll
    for (int mi = 0; mi < 4; mi++) {
        #pragma unroll
        for (int ni = 0; ni < 4; ni++) {
            #pragma unroll
            for (int q = 0; q < 4; q++) {
                int row = bm + wm * 64 + mi * 16 + cr + q;
                int col = bn + wn * 64 + ni * 16 + cc;
                float v = acc[mi][ni][q];
                if (EPI == 1) {
                    int half = N >> 1;
                    if (col < half) ((u16*)C0v)[(size_t)row * half + col] = f2h_bits(v);
                    else            ((u16*)C1v)[(size_t)row * half + col - half] = f2h_bits(siluf(v));
                } else {
                    ((u16*)C0v)[((size_t)blockIdx.z * M + row) * N + col] = f2h_bits(v);
                }
            }
        }
    }
}

// ---------------- sum the two split-K f16 partials -> fp32 out ----------------
__global__ __launch_bounds__(256)
void add_partials(const u16* __restrict__ p, float* __restrict__ out)
{
    int i = blockIdx.x * 256 + threadIdx.x;        // over 4096*1024/8
    short8 a = *(const short8*)&p[(size_t)i * 8];
    short8 b = *(const short8*)&p[(size_t)NROWS * DMOD + (size_t)i * 8];
    float4 o0, o1;
    o0.x = h2f((u16)a[0]) + h2f((u16)b[0]);
    o0.y = h2f((u16)a[1]) + h2f((u16)b[1]);
    o0.z = h2f((u16)a[2]) + h2f((u16)b[2]);
    o0.w = h2f((u16)a[3]) + h2f((u16)b[3]);
    o1.x = h2f((u16)a[4]) + h2f((u16)b[4]);
    o1.y = h2f((u16)a[5]) + h2f((u16)b[5]);
    o1.z = h2f((u16)a[6]) + h2f((u16)b[6]);
    o1.w = h2f((u16)a[7]) + h2f((u16)b[7]);
    *(float4*)&out[(size_t)i * 8]     = o0;
    *(float4*)&out[(size_t)i * 8 + 4] = o1;
}

// ---------------- depthwise causal conv + bias + SiLU, LDS-tiled (32t x 128d / block) ----
__global__ __launch_bounds__(256)
void conv_silu16t(const u16* __restrict__ xin16, const float* __restrict__ cw,
                  const float* __restrict__ cb, u16* __restrict__ xc16)
{
    __shared__ u16 sx[35][136];                    // padded stride: conflict-free reads
    const int d0 = blockIdx.x << 7, t0 = blockIdx.y << 5, b = blockIdx.z;
    const int tid = threadIdx.x;
    for (int i = tid; i < 35 * 16; i += 256) {
        int r = i >> 4, u = i & 15;
        int t = t0 - 3 + r;
        short8 v = {0,0,0,0,0,0,0,0};
        if (t >= 0) v = *(const short8*)&xin16[((size_t)(b * L_SEQ + t)) * DIN + d0 + u * 8];
        *(short8*)&sx[r][u * 8] = v;
    }
    __syncthreads();
    const int u  = tid & 15;
    const int tl = tid >> 4;
    const int d  = d0 + u * 8;
    const float4* cw4 = (const float4*)cw;
    float4 w[8];
    #pragma unroll
    for (int j = 0; j < 8; j++) w[j] = cw4[d + j];
    float bias[8];
    {
        float4 b0 = *(const float4*)&cb[d];
        float4 b1 = *(const float4*)&cb[d + 4];
        bias[0]=b0.x; bias[1]=b0.y; bias[2]=b0.z; bias[3]=b0.w;
        bias[4]=b1.x; bias[5]=b1.y; bias[6]=b1.z; bias[7]=b1.w;
    }
    #pragma unroll
    for (int half = 0; half < 2; half++) {
        const int t_l = tl + half * 16;
        float acc[8];
        #pragma unroll
        for (int j = 0; j < 8; j++) acc[j] = bias[j];
        #pragma unroll
        for (int k = 0; k < 4; k++) {
            short8 v = *(const short8*)&sx[t_l + k][u * 8];
            #pragma unroll
            for (int j = 0; j < 8; j++)
                acc[j] = fmaf(h2f((u16)v[j]), (&w[j].x)[k], acc[j]);
        }
        short8 o;
        #pragma unroll
        for (int j = 0; j < 8; j++) o[j] = (short)f2h_bits(siluf(acc[j]));
        *(short8*)&xc16[((size_t)(b * L_SEQ + t0 + t_l)) * DIN + d] = o;
    }
}

// ---------------- GEMM2: [4096][2048] @ [48][2048]^T, K-split 8, tile M=64 ----------------
__global__ __launch_bounds__(256)
void gemm2_mfma(const u16* __restrict__ A, const u16* __restrict__ Bt, float* __restrict__ pb)
{
    __shared__ __align__(16) u16 As[64 * 64];
    __shared__ __align__(16) u16 Bs[48 * 64];
    const int tid = threadIdx.x, lane = tid & 63, w = tid >> 6;
    const int bm = blockIdx.x * 64;
    const int kz = blockIdx.y;
    const int arow = tid >> 2;
    const int au   = (tid & 3) << 1;
    f32x4 acc[3];
    acc[0] = acc[1] = acc[2] = (f32x4){0.f, 0.f, 0.f, 0.f};

    for (int it = 0; it < 4; ++it) {
        const int k0 = kz * 256 + it * 64;
        short8 ra0 = *(const short8*)&A[(size_t)(bm + arow) * DIN + k0 + au * 8];
        short8 ra1 = *(const short8*)&A[(size_t)(bm + arow) * DIN + k0 + (au + 1) * 8];
        short8 rb0, rb1;
        if (tid < 192) {
            rb0 = *(const short8*)&Bt[(size_t)arow * DIN + k0 + au * 8];
            rb1 = *(const short8*)&Bt[(size_t)arow * DIN + k0 + (au + 1) * 8];
        }
        __syncthreads();
        {
            int s0 = au ^ (arow & 7), s1 = (au + 1) ^ (arow & 7);
            *(short8*)&As[arow * 64 + s0 * 8] = ra0;
            *(short8*)&As[arow * 64 + s1 * 8] = ra1;
            if (tid < 192) {
                *(short8*)&Bs[arow * 64 + s0 * 8] = rb0;
                *(short8*)&Bs[arow * 64 + s1 * 8] = rb1;
            }
        }
        __syncthreads();
        #pragma unroll
        for (int kk = 0; kk < 2; kk++) {
            int r = w * 16 + (lane & 15);
            int sl = (kk * 4 + (lane >> 4)) ^ (r & 7);
            half8 af = *(const half8*)&As[r * 64 + sl * 8];
            #pragma unroll
            for (int ni = 0; ni < 3; ni++) {
                int br = ni * 16 + (lane & 15);
                int bsl = (kk * 4 + (lane >> 4)) ^ (br & 7);
                half8 bf = *(const half8*)&Bs[br * 64 + bsl * 8];
                acc[ni] = __builtin_amdgcn_mfma_f32_16x16x32_f16(af, bf, acc[ni], 0, 0, 0);
            }
        }
    }
    #pragma unroll
    for (int ni = 0; ni < 3; ni++) {
        #pragma unroll
        for (int q = 0; q < 4; q++) {
            int row = bm + w * 16 + (lane >> 4) * 4 + q;
            int col = ni * 16 + (lane & 15);
            pb[((size_t)kz * NROWS + row) * 48 + col] = acc[ni][q];
        }
    }
}

// ---------------- GEMM2 reduce: sum 8 partials, softplus col0, split B/C ----------------
__global__ __launch_bounds__(256)
void gemm2_reduce(const float* __restrict__ pb, float* __restrict__ delta,
                  float* __restrict__ Bm, float* __restrict__ Cm)
{
    int idx = blockIdx.x * 256 + threadIdx.x;      // 4096*48
    int row = idx / 48, col = idx - row * 48;
    float s = 0.f;
    #pragma unroll
    for (int kz = 0; kz < 8; kz++) s += pb[(size_t)kz * NROWS * 48 + idx];
    if (col == 0)       delta[row] = fmaxf(s, 0.f) + log1pf(__expf(-fabsf(s)));
    else if (col < 17)  Bm[row * NST + col - 1]  = s;
    else if (col < 33)  Cm[row * NST + col - 17] = s;
}

// ---------------- scan pass 1: thread-per-d, h[16] in regs ----------------
__global__ __launch_bounds__(256)
void scan_part1_reg(const u16* __restrict__ xc16, const float* __restrict__ delta,
                    const float* __restrict__ Bm, const float* __restrict__ A_log,
                    float* __restrict__ h_loc, float* __restrict__ Pc)
{
    const int b = blockIdx.z, c = blockIdx.y;
    const int d = blockIdx.x * 256 + threadIdx.x;
    float ka[16];
    {
        const float4* Av = (const float4*)(A_log + (size_t)d * 16);
        #pragma unroll
        for (int q = 0; q < 4; q++) {
            float4 a = Av[q];
            ka[q*4+0] = -__expf(a.x) * 1.44269504f;
            ka[q*4+1] = -__expf(a.y) * 1.44269504f;
            ka[q*4+2] = -__expf(a.z) * 1.44269504f;
            ka[q*4+3] = -__expf(a.w) * 1.44269504f;
        }
    }
    float h[16];
    #pragma unroll
    for (int n = 0; n < 16; n++) h[n] = 0.f;
    float S = 0.f;
    const int rowbase = b * L_SEQ + c * CL;
    #pragma unroll 2
    for (int t = 0; t < CL; ++t) {
        const int rowg = rowbase + t;
        const float dt = delta[rowg];
        const float4* Bv = (const float4*)(Bm + (size_t)rowg * 16);
        float4 b0 = Bv[0], b1 = Bv[1], b2 = Bv[2], b3 = Bv[3];
        float bb[16] = {b0.x,b0.y,b0.z,b0.w, b1.x,b1.y,b1.z,b1.w,
                        b2.x,b2.y,b2.z,b2.w, b3.x,b3.y,b3.z,b3.w};
        const float xt = h2f(xc16[(size_t)rowg * DIN + d]);
        const float dtx = dt * xt;
        S += dt;
        #pragma unroll
        for (int n = 0; n < 16; n++) {
            float a = fexp2(dt * ka[n]);
            h[n] = fmaf(a, h[n], bb[n] * dtx);
        }
    }
    float* hp = h_loc + (((size_t)(b * NC + c) * DIN) + d) * 16;
    float* pp = Pc    + (((size_t)(b * NC + c) * DIN) + d) * 16;
    #pragma unroll
    for (int q = 0; q < 4; q++) {
        *(float4*)&hp[q*4] = (float4){h[q*4+0], h[q*4+1], h[q*4+2], h[q*4+3]};
        *(float4*)&pp[q*4] = (float4){fexp2(S*ka[q*4+0]), fexp2(S*ka[q*4+1]),
                                      fexp2(S*ka[q*4+2]), fexp2(S*ka[q*4+3])};
    }
}

// ---------------- scan pass 2: sequential carry across chunks ----------------
__global__ __launch_bounds__(256)
void scan_carry(const float* __restrict__ h_loc, const float* __restrict__ Pc,
                float* __restrict__ H_in)
{
    int gid = blockIdx.x * 256 + threadIdx.x;      // NB*DIN*NST = 65536
    int b = gid >> 15, r = gid & 32767;
    float H = 0.f;
    for (int c = 0; c < NC; ++c) {
        size_t idx = ((size_t)(b * NC + c) << 15) + r;
        H_in[idx] = H;
        H = fmaf(Pc[idx], H, h_loc[idx]);
    }
}

// ---------------- scan pass 3: thread-per-d, fused epilogue -> y fp16 ----------------
__global__ __launch_bounds__(256)
void scan_part3_reg(const u16* __restrict__ xc16, const float* __restrict__ delta,
                    const float* __restrict__ Bm, const float* __restrict__ Cm,
                    const float* __restrict__ A_log, const float* __restrict__ Dp,
                    const u16* __restrict__ res16, const float* __restrict__ H_in,
                    u16* __restrict__ yh)
{
    const int b = blockIdx.z, c = blockIdx.y;
    const int d = blockIdx.x * 256 + threadIdx.x;
    float ka[16];
    {
        const float4* Av = (const float4*)(A_log + (size_t)d * 16);
        #pragma unroll
        for (int q = 0; q < 4; q++) {
            float4 a = Av[q];
            ka[q*4+0] = -__expf(a.x) * 1.44269504f;
            ka[q*4+1] = -__expf(a.y) * 1.44269504f;
            ka[q*4+2] = -__expf(a.z) * 1.44269504f;
            ka[q*4+3] = -__expf(a.w) * 1.44269504f;
        }
    }
    float h[16];
    {
        const float4* Hv = (const float4*)(H_in + (((size_t)(b * NC + c) * DIN) + d) * 16);
        #pragma unroll
        for (int q = 0; q < 4; q++) {
            float4 v = Hv[q];
            h[q*4+0]=v.x; h[q*4+1]=v.y; h[q*4+2]=v.z; h[q*4+3]=v.w;
        }
    }
    const float Dpd = Dp[d];
    const int rowbase = b * L_SEQ + c * CL;
    #pragma unroll 2
    for (int t = 0; t < CL; ++t) {
        const int rowg = rowbase + t;
        const float dt = delta[rowg];
        const float4* Bv = (const float4*)(Bm + (size_t)rowg * 16);
        const float4* Cv = (const float4*)(Cm + (size_t)rowg * 16);
        float4 b0 = Bv[0], b1 = Bv[1], b2 = Bv[2], b3 = Bv[3];
        float4 c0 = Cv[0], c1 = Cv[1], c2 = Cv[2], c3 = Cv[3];
        float bb[16] = {b0.x,b0.y,b0.z,b0.w, b1.x,b1.y,b1.z,b1.w,
                        b2.x,b2.y,b2.z,b2.w, b3.x,b3.y,b3.z,b3.w};
        float cc[16] = {c0.x,c0.y,c0.z,c0.w, c1.x,c1.y,c1.z,c1.w,
                        c2.x,c2.y,c2.z,c2.w, c3.x,c3.y,c3.z,c3.w};
        const float xt = h2f(xc16[(size_t)rowg * DIN + d]);
        const float rt = h2f(res16[(size_t)rowg * DIN + d]);
        const float dtx = dt * xt;
        float y = 0.f;
        #pragma unroll
        for (int n = 0; n < 16; n++) {
            float a = fexp2(dt * ka[n]);
            h[n] = fmaf(a, h[n], bb[n] * dtx);
            y = fmaf(cc[n], h[n], y);
        }
        y = (y + xt * Dpd) * rt;
        yh[(size_t)rowg * DIN + d] = f2h_bits(y);
    }
}

extern "C" void kernel_launch(void* const* d_in, const int* in_sizes, int n_in,
                              void* d_out, int out_size, void* d_ws, size_t ws_size,
                              hipStream_t stream)
{
    const float* x     = (const float*)d_in[0];
    const float* W_in  = (const float*)d_in[1];
    const float* cw    = (const float*)d_in[2];
    const float* cb    = (const float*)d_in[3];
    const float* Wx    = (const float*)d_in[4];
    const float* A_log = (const float*)d_in[5];
    const float* Dp    = (const float*)d_in[6];
    const float* W_out = (const float*)d_in[7];
    float* out = (float*)d_out;
    float* ws  = (float*)d_ws;

    // workspace (float slot offsets); aliases valid by stream-order lifetimes
    u16*   xin16 = (u16*)(ws);                     // [4096][2048] ; dead after conv
    u16*   y16   = (u16*)(ws);                     // alias
    u16*   res16 = (u16*)(ws + 4194304);           // [4096][2048]
    u16*   xc16  = (u16*)(ws + 8388608);           // [4096][2048]
    u16*   x16   = (u16*)(ws + 12582912);          // [4096][1024] ; dead after GEMM1
    u16*   p2    = (u16*)(ws + 12582912);          // [2][4096][1024] (alias x16+Bt1)
    u16*   Bt1   = (u16*)(ws + 14680064);          // [4096][1024] ; dead after GEMM1
    float* pb    = ws + 14680064;                  // [8][4096][48] f32 (dead before GEMM3)
    u16*   WxT16 = (u16*)(ws + 20971520);          // [48][2048]
    float* delta = ws + 21020672;                  // 4096
    float* Bm    = ws + 21024768;                  // 65536
    float* Cm    = ws + 21090304;                  // 65536
    float* h_loc = ws + 21155840;                  // 2097152
    float* Pc    = ws + 23252992;                  // 2097152
    float* H_in  = ws + 25350144;                  // 2097152
    u16*   Bt3   = (u16*)(ws + 27447296);          // [1024][2048] (end 28495872 fl = 114 MB)

    dim3 blk(256);

    // 1) fused preprocessing
    prep_inputs<<<dim3(6016), blk, 0, stream>>>(x, W_in, W_out, Wx, x16, Bt1, Bt3, WxT16);
    // 2) GEMM1 (gemm97): xin16 | silu(res)16 ; grid 32x32 = 1024 blocks, 3/CU resident
    gemm97<1><<<dim3(32, 32, 1), blk, 0, stream>>>(x16, Bt1, xin16, res16,
                                                   NROWS, 2 * DIN, DMOD, DMOD, DMOD);
    // 3) conv + bias + silu (LDS-tiled)
    conv_silu16t<<<dim3(DIN / 128, L_SEQ / 32, NB), blk, 0, stream>>>(xin16, cw, cb, xc16);
    // 4) ssm params
    gemm2_mfma<<<dim3(NROWS / 64, 8), blk, 0, stream>>>(xc16, WxT16, pb);
    gemm2_reduce<<<dim3(NROWS * 48 / 256), blk, 0, stream>>>(pb, delta, Bm, Cm);
    // 5) chunk-parallel scan
    scan_part1_reg<<<dim3(DIN / 256, NC, NB), blk, 0, stream>>>(xc16, delta, Bm, A_log, h_loc, Pc);
    scan_carry<<<dim3(NB * DIN * NST / 256), blk, 0, stream>>>(h_loc, Pc, H_in);
    scan_part3_reg<<<dim3(DIN / 256, NC, NB), blk, 0, stream>>>(xc16, delta, Bm, Cm, A_log, Dp, res16, H_in, y16);
    // 6) GEMM3 (gemm97, split-K=2): grid (8,32,2) = 512 blocks, KLEN=1024
    gemm97<2><<<dim3(DMOD / 128, NROWS / 128, 2), blk, 0, stream>>>(y16, Bt3, p2, nullptr,
                                                                   NROWS, DMOD, DIN / 2, DIN, DIN);
    // 7) out = p[0] + p[1] (fp32)
    add_partials<<<dim3(NROWS * DMOD / 8 / 256), blk, 0, stream>>>(p2, out);
}

// Round 12
// 187.162 us; speedup vs baseline: 1.0900x; 1.0900x over previous
//
#include <hip/hip_runtime.h>

#define L_SEQ 2048
#define NB    2
#define DMOD  1024
#define DIN   2048
#define NST   16
#define NROWS (NB*L_SEQ)   // 4096
#define CL    64
#define NC    (L_SEQ/CL)   // 32

typedef unsigned short u16;
typedef _Float16 half8 __attribute__((ext_vector_type(8)));
typedef float f32x4 __attribute__((ext_vector_type(4)));
typedef short short8 __attribute__((ext_vector_type(8)));

__device__ __forceinline__ float siluf(float v){ return v / (1.f + __expf(-v)); }
__device__ __forceinline__ u16 f2h_bits(float v){ _Float16 h = (_Float16)v; return __builtin_bit_cast(u16, h); }
__device__ __forceinline__ float h2f(u16 v){ return (float)__builtin_bit_cast(_Float16, v); }
__device__ __forceinline__ float fexp2(float x){
#if __has_builtin(__builtin_amdgcn_exp2f)
    return __builtin_amdgcn_exp2f(x);
#else
    return __expf(x * 0.69314718056f);
#endif
}

// async global->LDS, 16B per lane; lds base wave-uniform; dest = base + lane*16
__device__ __forceinline__ void gload16(const u16* g, u16* l)
{
    __builtin_amdgcn_global_load_lds(
        (const __attribute__((address_space(1))) void*)g,
        (__attribute__((address_space(3))) void*)l,
        16, 0, 0);
}

#define BARRIER() do { asm volatile("" ::: "memory"); __builtin_amdgcn_s_barrier(); asm volatile("" ::: "memory"); } while (0)
#define VMCNT0()  asm volatile("s_waitcnt vmcnt(0)" ::: "memory")
#define VMCNT2()  asm volatile("s_waitcnt vmcnt(2)" ::: "memory")
#define VMCNT8()  asm volatile("s_waitcnt vmcnt(8)" ::: "memory")

// ---------------- fused input preprocessing ----------------
__global__ __launch_bounds__(256)
void prep_inputs(const float* __restrict__ x, const float* __restrict__ W_in,
                 const float* __restrict__ W_out, const float* __restrict__ Wx,
                 u16* __restrict__ x16, u16* __restrict__ Bt1,
                 u16* __restrict__ Bt3, u16* __restrict__ WxT16)
{
    __shared__ float s[64][65];
    const int bid = blockIdx.x, tid = threadIdx.x;
    if (bid < 4096) {
        int i = bid * 256 + tid;                   // over NROWS*DMOD/4
        float4 v = ((const float4*)x)[i];
        ushort4 o;
        o.x = f2h_bits(v.x); o.y = f2h_bits(v.y); o.z = f2h_bits(v.z); o.w = f2h_bits(v.w);
        *(ushort4*)&x16[(size_t)i * 4] = o;
    } else if (bid < 5632) {
        const float* in; u16* outT; int R, C, rblk, cblk;
        if (bid < 5120) { int b = bid - 4096; in = W_in;  outT = Bt1; R = 1024; C = 4096; cblk = b & 63; rblk = b >> 6; }
        else            { int b = bid - 5120; in = W_out; outT = Bt3; R = 2048; C = 1024; cblk = b & 15; rblk = b >> 4; }
        int r0 = rblk * 64, c0 = cblk * 64;
        int tc = tid & 63, ty = tid >> 6;
        #pragma unroll
        for (int j = 0; j < 16; j++) {
            int r = ty + j * 4;
            s[r][tc] = in[(size_t)(r0 + r) * C + c0 + tc];
        }
        __syncthreads();
        #pragma unroll
        for (int j = 0; j < 16; j++) {
            int nn = ty + j * 4;
            outT[(size_t)(c0 + nn) * R + r0 + tc] = f2h_bits(s[tc][nn]);
        }
    } else {
        int idx = (bid - 5632) * 256 + tid;        // 48*2048
        int n = idx >> 11, k = idx & 2047;
        float v = (n < 33) ? Wx[k * 33 + n] : 0.f;
        WxT16[idx] = f2h_bits(v);
    }
}

// ---------------- 4-phase MFMA GEMM: 256x256 tile, BK=64, 8 waves, 512 thr (round-10) ----
// EPI==1: split N at half: col<half -> C0h (u16) ; else C1h = silu (u16)
template<int EPI>
__global__ __launch_bounds__(512, 2)
void gemm8(const u16* __restrict__ A, const u16* __restrict__ Bt,
           void* __restrict__ C0v, void* __restrict__ C1v,
           int M, int N, int KLEN, int lda, int ldb)
{
    __shared__ __align__(16) u16 As[2 * 256 * 64];   // 64 KB (2 bufs)
    __shared__ __align__(16) u16 Bs[2 * 256 * 64];   // 64 KB
    const int tid  = threadIdx.x;
    const int lane = tid & 63;
    const int w    = tid >> 6;                 // 0..7
    const int wm   = w >> 2, wn = w & 3;       // 2 x 4 wave grid
    const int bm = blockIdx.y * 256, bn = blockIdx.x * 256;
    const int kBase = blockIdx.z * KLEN;

    const int srow8 = lane >> 3;
    const int sunit = (lane & 7) ^ srow8;
    const u16* Ag = A  + (size_t)(bm + srow8) * lda + kBase + sunit * 8;
    const u16* Bg = Bt + (size_t)(bn + srow8) * ldb + kBase + sunit * 8;
    const int rw = w * 16;

    const int fr  = lane & 15;
    const int sl0 = ((lane >> 4) ^ (fr & 7)) * 8;
    int aOffs[8], bOffs[4];
    #pragma unroll
    for (int mi = 0; mi < 8; mi++) aOffs[mi] = (wm * 128 + mi * 16 + fr) * 64 + sl0;
    #pragma unroll
    for (int ni = 0; ni < 4; ni++) bOffs[ni] = (ni * 64 + wn * 16 + fr) * 64 + sl0;

    f32x4 acc[8][4];
    #pragma unroll
    for (int i = 0; i < 8; i++)
        #pragma unroll
        for (int j = 0; j < 4; j++)
            acc[i][j] = (f32x4){0.f, 0.f, 0.f, 0.f};

    auto stage2 = [&](const u16* G, int ld, int rbase, int kcol, u16* ldsDst) {
        gload16(G + (size_t)rbase * ld + kcol, ldsDst);
        gload16(G + (size_t)(rbase + 8) * ld + kcol, ldsDst + 8 * 64);
    };

    const int NT = KLEN >> 6;
    stage2(Ag, lda, 0 + rw, 0, &As[(0 + rw) * 64]);
    stage2(Ag, lda, 128 + rw, 0, &As[(128 + rw) * 64]);
    stage2(Bg, ldb, 0 + rw, 0, &Bs[(0 + rw) * 64]);
    stage2(Bg, ldb, 128 + rw, 0, &Bs[(128 + rw) * 64]);
    VMCNT2();
    BARRIER();

    for (int t = 0; t < NT; ++t) {
        const int cO = (t & 1) << 14;
        const int nO = cO ^ 16384;
        const int kn = (t + 1) << 6;
        const bool pf = (t + 1) < NT;
        half8 af[8], bf0, bf1;

        // ---- phase 0
        #pragma unroll
        for (int mi = 0; mi < 8; mi++) af[mi] = *(const half8*)&As[cO + aOffs[mi]];
        bf0 = *(const half8*)&Bs[cO + bOffs[0]];
        bf1 = *(const half8*)&Bs[cO + bOffs[1]];
        if (pf) stage2(Ag, lda, 0 + rw, kn, &As[nO + (0 + rw) * 64]);
        BARRIER();
        #pragma unroll
        for (int mi = 0; mi < 8; mi++) acc[mi][0] = __builtin_amdgcn_mfma_f32_16x16x32_f16(af[mi], bf0, acc[mi][0], 0, 0, 0);
        #pragma unroll
        for (int mi = 0; mi < 8; mi++) acc[mi][1] = __builtin_amdgcn_mfma_f32_16x16x32_f16(af[mi], bf1, acc[mi][1], 0, 0, 0);
        VMCNT2();
        BARRIER();

        // ---- phase 1
        bf0 = *(const half8*)&Bs[cO + bOffs[2]];
        bf1 = *(const half8*)&Bs[cO + bOffs[3]];
        if (pf) stage2(Ag, lda, 128 + rw, kn, &As[nO + (128 + rw) * 64]);
        BARRIER();
        #pragma unroll
        for (int mi = 0; mi < 8; mi++) acc[mi][2] = __builtin_amdgcn_mfma_f32_16x16x32_f16(af[mi], bf0, acc[mi][2], 0, 0, 0);
        #pragma unroll
        for (int mi = 0; mi < 8; mi++) acc[mi][3] = __builtin_amdgcn_mfma_f32_16x16x32_f16(af[mi], bf1, acc[mi][3], 0, 0, 0);
        BARRIER();

        // ---- phase 2
        #pragma unroll
        for (int mi = 0; mi < 8; mi++) af[mi] = *(const half8*)&As[cO + (aOffs[mi] ^ 32)];
        bf0 = *(const half8*)&Bs[cO + (bOffs[0] ^ 32)];
        bf1 = *(const half8*)&Bs[cO + (bOffs[1] ^ 32)];
        if (pf) stage2(Bg, ldb, 0 + rw, kn, &Bs[nO + (0 + rw) * 64]);
        BARRIER();
        #pragma unroll
        for (int mi = 0; mi < 8; mi++) acc[mi][0] = __builtin_amdgcn_mfma_f32_16x16x32_f16(af[mi], bf0, acc[mi][0], 0, 0, 0);
        #pragma unroll
        for (int mi = 0; mi < 8; mi++) acc[mi][1] = __builtin_amdgcn_mfma_f32_16x16x32_f16(af[mi], bf1, acc[mi][1], 0, 0, 0);
        BARRIER();

        // ---- phase 3
        bf0 = *(const half8*)&Bs[cO + (bOffs[2] ^ 32)];
        bf1 = *(const half8*)&Bs[cO + (bOffs[3] ^ 32)];
        if (pf) stage2(Bg, ldb, 128 + rw, kn, &Bs[nO + (128 + rw) * 64]);
        BARRIER();
        #pragma unroll
        for (int mi = 0; mi < 8; mi++) acc[mi][2] = __builtin_amdgcn_mfma_f32_16x16x32_f16(af[mi], bf0, acc[mi][2], 0, 0, 0);
        #pragma unroll
        for (int mi = 0; mi < 8; mi++) acc[mi][3] = __builtin_amdgcn_mfma_f32_16x16x32_f16(af[mi], bf1, acc[mi][3], 0, 0, 0);
        VMCNT2();
        BARRIER();
    }

    const int cr = (lane >> 4) * 4;
    #pragma unroll
    for (int mi = 0; mi < 8; mi++) {
        #pragma unroll
        for (int ni = 0; ni < 4; ni++) {
            #pragma unroll
            for (int q = 0; q < 4; q++) {
                int row = bm + wm * 128 + mi * 16 + cr + q;
                int col = bn + ni * 64 + wn * 16 + fr;
                float v = acc[mi][ni][q];
                int half = N >> 1;
                if (col < half) ((u16*)C0v)[(size_t)row * half + col] = f2h_bits(v);
                else            ((u16*)C1v)[(size_t)row * half + col - half] = f2h_bits(siluf(v));
            }
        }
    }
}

// ---------------- gemm128c: 128x128, BK=64, 4 waves, dbuf, COUNTED vmcnt(8) ----
// One compute phase per K-tile; raw barriers; vmcnt(8) leaves next tile's loads in flight.
// 64KB LDS -> 2 blocks/CU resident (cross-block overlap covers barrier waits).
// EPI==2: u16 partial at C0[(z*M + row)*N + col]
__global__ __launch_bounds__(256, 2)
void gemm128c(const u16* __restrict__ A, const u16* __restrict__ Bt,
              u16* __restrict__ C0, int M, int N, int KLEN, int lda, int ldb)
{
    __shared__ __align__(16) u16 As[2 * 128 * 64];   // 32 KB
    __shared__ __align__(16) u16 Bs[2 * 128 * 64];   // 32 KB
    const int tid  = threadIdx.x;
    const int lane = tid & 63;
    const int wid  = tid >> 6;
    const int wm   = wid >> 1, wn = wid & 1;
    const int bm = blockIdx.y * 128, bn = blockIdx.x * 128;
    const int kBase = blockIdx.z * KLEN;

    const int srow8 = lane >> 3;
    const int sunit = (lane & 7) ^ srow8;
    const u16* Ag = A  + (size_t)(bm + srow8) * lda + kBase + sunit * 8;
    const u16* Bg = Bt + (size_t)(bn + srow8) * ldb + kBase + sunit * 8;

    const int fr = lane & 15;
    const int s0 = ((lane >> 4) ^ (lane & 7)) * 8;
    const int aBase = (wm * 64 + fr) * 64 + s0;
    const int bBase = (wn * 64 + fr) * 64 + s0;

    f32x4 acc[4][4];
    #pragma unroll
    for (int i = 0; i < 4; i++)
        #pragma unroll
        for (int j = 0; j < 4; j++)
            acc[i][j] = (f32x4){0.f, 0.f, 0.f, 0.f};

    auto STAGE = [&](int bufO, int k0) {              // 8 gloads per wave
        #pragma unroll
        for (int j = 0; j < 4; j++) {
            int c = wid * 4 + j;                      // 0..15: rows c*8..c*8+7
            gload16(Ag + (size_t)(c * 8) * lda + k0, &As[bufO + c * 512]);
            gload16(Bg + (size_t)(c * 8) * ldb + k0, &Bs[bufO + c * 512]);
        }
    };

    auto COMPUTE = [&](int bufO) {
        #pragma unroll
        for (int kk = 0; kk < 2; kk++) {
            const int x = kk ? 32 : 0;
            half8 af[4], bf[4];
            #pragma unroll
            for (int mi = 0; mi < 4; mi++)
                af[mi] = *(const half8*)&As[bufO + (aBase ^ x) + mi * 1024];
            #pragma unroll
            for (int ni = 0; ni < 4; ni++)
                bf[ni] = *(const half8*)&Bs[bufO + (bBase ^ x) + ni * 1024];
            #pragma unroll
            for (int mi = 0; mi < 4; mi++)
                #pragma unroll
                for (int ni = 0; ni < 4; ni++)
                    acc[mi][ni] = __builtin_amdgcn_mfma_f32_16x16x32_f16(af[mi], bf[ni], acc[mi][ni], 0, 0, 0);
        }
    };

    const int NT = KLEN >> 6;                          // 16
    STAGE(0, 0);
    int buf = 0;
    for (int t = 0; t < NT; ++t) {
        if (t + 1 < NT) { STAGE(buf ^ 8192, (t + 1) << 6); VMCNT8(); }
        else            { VMCNT0(); }
        BARRIER();                                      // tile t visible to all waves
        COMPUTE(buf);
        BARRIER();                                      // reads of buf done before next overwrite
        buf ^= 8192;
    }

    const int cr = (lane >> 4) * 4;
    const int cc = lane & 15;
    #pragma unroll
    for (int mi = 0; mi < 4; mi++) {
        #pragma unroll
        for (int ni = 0; ni < 4; ni++) {
            #pragma unroll
            for (int q = 0; q < 4; q++) {
                int row = bm + wm * 64 + mi * 16 + cr + q;
                int col = bn + wn * 64 + ni * 16 + cc;
                C0[((size_t)blockIdx.z * M + row) * N + col] = f2h_bits(acc[mi][ni][q]);
            }
        }
    }
}

// ---------------- sum the two split-K f16 partials -> fp32 out ----------------
__global__ __launch_bounds__(256)
void add_partials(const u16* __restrict__ p, float* __restrict__ out)
{
    int i = blockIdx.x * 256 + threadIdx.x;        // over 4096*1024/8
    short8 a = *(const short8*)&p[(size_t)i * 8];
    short8 b = *(const short8*)&p[(size_t)NROWS * DMOD + (size_t)i * 8];
    float4 o0, o1;
    o0.x = h2f((u16)a[0]) + h2f((u16)b[0]);
    o0.y = h2f((u16)a[1]) + h2f((u16)b[1]);
    o0.z = h2f((u16)a[2]) + h2f((u16)b[2]);
    o0.w = h2f((u16)a[3]) + h2f((u16)b[3]);
    o1.x = h2f((u16)a[4]) + h2f((u16)b[4]);
    o1.y = h2f((u16)a[5]) + h2f((u16)b[5]);
    o1.z = h2f((u16)a[6]) + h2f((u16)b[6]);
    o1.w = h2f((u16)a[7]) + h2f((u16)b[7]);
    *(float4*)&out[(size_t)i * 8]     = o0;
    *(float4*)&out[(size_t)i * 8 + 4] = o1;
}

// ---------------- depthwise causal conv + bias + SiLU, LDS-tiled (32t x 128d / block) ----
__global__ __launch_bounds__(256)
void conv_silu16t(const u16* __restrict__ xin16, const float* __restrict__ cw,
                  const float* __restrict__ cb, u16* __restrict__ xc16)
{
    __shared__ u16 sx[35][136];
    const int d0 = blockIdx.x << 7, t0 = blockIdx.y << 5, b = blockIdx.z;
    const int tid = threadIdx.x;
    for (int i = tid; i < 35 * 16; i += 256) {
        int r = i >> 4, u = i & 15;
        int t = t0 - 3 + r;
        short8 v = {0,0,0,0,0,0,0,0};
        if (t >= 0) v = *(const short8*)&xin16[((size_t)(b * L_SEQ + t)) * DIN + d0 + u * 8];
        *(short8*)&sx[r][u * 8] = v;
    }
    __syncthreads();
    const int u  = tid & 15;
    const int tl = tid >> 4;
    const int d  = d0 + u * 8;
    const float4* cw4 = (const float4*)cw;
    float4 w[8];
    #pragma unroll
    for (int j = 0; j < 8; j++) w[j] = cw4[d + j];
    float bias[8];
    {
        float4 b0 = *(const float4*)&cb[d];
        float4 b1 = *(const float4*)&cb[d + 4];
        bias[0]=b0.x; bias[1]=b0.y; bias[2]=b0.z; bias[3]=b0.w;
        bias[4]=b1.x; bias[5]=b1.y; bias[6]=b1.z; bias[7]=b1.w;
    }
    #pragma unroll
    for (int half = 0; half < 2; half++) {
        const int t_l = tl + half * 16;
        float acc[8];
        #pragma unroll
        for (int j = 0; j < 8; j++) acc[j] = bias[j];
        #pragma unroll
        for (int k = 0; k < 4; k++) {
            short8 v = *(const short8*)&sx[t_l + k][u * 8];
            #pragma unroll
            for (int j = 0; j < 8; j++)
                acc[j] = fmaf(h2f((u16)v[j]), (&w[j].x)[k], acc[j]);
        }
        short8 o;
        #pragma unroll
        for (int j = 0; j < 8; j++) o[j] = (short)f2h_bits(siluf(acc[j]));
        *(short8*)&xc16[((size_t)(b * L_SEQ + t0 + t_l)) * DIN + d] = o;
    }
}

// ---------------- GEMM2: [4096][2048] @ [48][2048]^T, K-split 8, tile M=64 ----------------
__global__ __launch_bounds__(256)
void gemm2_mfma(const u16* __restrict__ A, const u16* __restrict__ Bt, float* __restrict__ pb)
{
    __shared__ __align__(16) u16 As[64 * 64];
    __shared__ __align__(16) u16 Bs[48 * 64];
    const int tid = threadIdx.x, lane = tid & 63, w = tid >> 6;
    const int bm = blockIdx.x * 64;
    const int kz = blockIdx.y;
    const int arow = tid >> 2;
    const int au   = (tid & 3) << 1;
    f32x4 acc[3];
    acc[0] = acc[1] = acc[2] = (f32x4){0.f, 0.f, 0.f, 0.f};

    for (int it = 0; it < 4; ++it) {
        const int k0 = kz * 256 + it * 64;
        short8 ra0 = *(const short8*)&A[(size_t)(bm + arow) * DIN + k0 + au * 8];
        short8 ra1 = *(const short8*)&A[(size_t)(bm + arow) * DIN + k0 + (au + 1) * 8];
        short8 rb0, rb1;
        if (tid < 192) {
            rb0 = *(const short8*)&Bt[(size_t)arow * DIN + k0 + au * 8];
            rb1 = *(const short8*)&Bt[(size_t)arow * DIN + k0 + (au + 1) * 8];
        }
        __syncthreads();
        {
            int s0 = au ^ (arow & 7), s1 = (au + 1) ^ (arow & 7);
            *(short8*)&As[arow * 64 + s0 * 8] = ra0;
            *(short8*)&As[arow * 64 + s1 * 8] = ra1;
            if (tid < 192) {
                *(short8*)&Bs[arow * 64 + s0 * 8] = rb0;
                *(short8*)&Bs[arow * 64 + s1 * 8] = rb1;
            }
        }
        __syncthreads();
        #pragma unroll
        for (int kk = 0; kk < 2; kk++) {
            int r = w * 16 + (lane & 15);
            int sl = (kk * 4 + (lane >> 4)) ^ (r & 7);
            half8 af = *(const half8*)&As[r * 64 + sl * 8];
            #pragma unroll
            for (int ni = 0; ni < 3; ni++) {
                int br = ni * 16 + (lane & 15);
                int bsl = (kk * 4 + (lane >> 4)) ^ (br & 7);
                half8 bf = *(const half8*)&Bs[br * 64 + bsl * 8];
                acc[ni] = __builtin_amdgcn_mfma_f32_16x16x32_f16(af, bf, acc[ni], 0, 0, 0);
            }
        }
    }
    #pragma unroll
    for (int ni = 0; ni < 3; ni++) {
        #pragma unroll
        for (int q = 0; q < 4; q++) {
            int row = bm + w * 16 + (lane >> 4) * 4 + q;
            int col = ni * 16 + (lane & 15);
            pb[((size_t)kz * NROWS + row) * 48 + col] = acc[ni][q];
        }
    }
}

// ---------------- GEMM2 reduce: sum 8 partials, softplus col0, split B/C ----------------
__global__ __launch_bounds__(256)
void gemm2_reduce(const float* __restrict__ pb, float* __restrict__ delta,
                  float* __restrict__ Bm, float* __restrict__ Cm)
{
    int idx = blockIdx.x * 256 + threadIdx.x;      // 4096*48
    int row = idx / 48, col = idx - row * 48;
    float s = 0.f;
    #pragma unroll
    for (int kz = 0; kz < 8; kz++) s += pb[(size_t)kz * NROWS * 48 + idx];
    if (col == 0)       delta[row] = fmaxf(s, 0.f) + log1pf(__expf(-fabsf(s)));
    else if (col < 17)  Bm[row * NST + col - 1]  = s;
    else if (col < 33)  Cm[row * NST + col - 17] = s;
}

// ---------------- scan pass 1: thread-per-d, h[16] in regs ----------------
__global__ __launch_bounds__(256)
void scan_part1_reg(const u16* __restrict__ xc16, const float* __restrict__ delta,
                    const float* __restrict__ Bm, const float* __restrict__ A_log,
                    float* __restrict__ h_loc, float* __restrict__ Pc)
{
    const int b = blockIdx.z, c = blockIdx.y;
    const int d = blockIdx.x * 256 + threadIdx.x;
    float ka[16];
    {
        const float4* Av = (const float4*)(A_log + (size_t)d * 16);
        #pragma unroll
        for (int q = 0; q < 4; q++) {
            float4 a = Av[q];
            ka[q*4+0] = -__expf(a.x) * 1.44269504f;
            ka[q*4+1] = -__expf(a.y) * 1.44269504f;
            ka[q*4+2] = -__expf(a.z) * 1.44269504f;
            ka[q*4+3] = -__expf(a.w) * 1.44269504f;
        }
    }
    float h[16];
    #pragma unroll
    for (int n = 0; n < 16; n++) h[n] = 0.f;
    float S = 0.f;
    const int rowbase = b * L_SEQ + c * CL;
    #pragma unroll 2
    for (int t = 0; t < CL; ++t) {
        const int rowg = rowbase + t;
        const float dt = delta[rowg];
        const float4* Bv = (const float4*)(Bm + (size_t)rowg * 16);
        float4 b0 = Bv[0], b1 = Bv[1], b2 = Bv[2], b3 = Bv[3];
        float bb[16] = {b0.x,b0.y,b0.z,b0.w, b1.x,b1.y,b1.z,b1.w,
                        b2.x,b2.y,b2.z,b2.w, b3.x,b3.y,b3.z,b3.w};
        const float xt = h2f(xc16[(size_t)rowg * DIN + d]);
        const float dtx = dt * xt;
        S += dt;
        #pragma unroll
        for (int n = 0; n < 16; n++) {
            float a = fexp2(dt * ka[n]);
            h[n] = fmaf(a, h[n], bb[n] * dtx);
        }
    }
    float* hp = h_loc + (((size_t)(b * NC + c) * DIN) + d) * 16;
    float* pp = Pc    + (((size_t)(b * NC + c) * DIN) + d) * 16;
    #pragma unroll
    for (int q = 0; q < 4; q++) {
        *(float4*)&hp[q*4] = (float4){h[q*4+0], h[q*4+1], h[q*4+2], h[q*4+3]};
        *(float4*)&pp[q*4] = (float4){fexp2(S*ka[q*4+0]), fexp2(S*ka[q*4+1]),
                                      fexp2(S*ka[q*4+2]), fexp2(S*ka[q*4+3])};
    }
}

// ---------------- scan pass 2: sequential carry across chunks ----------------
__global__ __launch_bounds__(256)
void scan_carry(const float* __restrict__ h_loc, const float* __restrict__ Pc,
                float* __restrict__ H_in)
{
    int gid = blockIdx.x * 256 + threadIdx.x;      // NB*DIN*NST = 65536
    int b = gid >> 15, r = gid & 32767;
    float H = 0.f;
    for (int c = 0; c < NC; ++c) {
        size_t idx = ((size_t)(b * NC + c) << 15) + r;
        H_in[idx] = H;
        H = fmaf(Pc[idx], H, h_loc[idx]);
    }
}

// ---------------- scan pass 3: thread-per-d, fused epilogue -> y fp16 ----------------
__global__ __launch_bounds__(256)
void scan_part3_reg(const u16* __restrict__ xc16, const float* __restrict__ delta,
                    const float* __restrict__ Bm, const float* __restrict__ Cm,
                    const float* __restrict__ A_log, const float* __restrict__ Dp,
                    const u16* __restrict__ res16, const float* __restrict__ H_in,
                    u16* __restrict__ yh)
{
    const int b = blockIdx.z, c = blockIdx.y;
    const int d = blockIdx.x * 256 + threadIdx.x;
    float ka[16];
    {
        const float4* Av = (const float4*)(A_log + (size_t)d * 16);
        #pragma unroll
        for (int q = 0; q < 4; q++) {
            float4 a = Av[q];
            ka[q*4+0] = -__expf(a.x) * 1.44269504f;
            ka[q*4+1] = -__expf(a.y) * 1.44269504f;
            ka[q*4+2] = -__expf(a.z) * 1.44269504f;
            ka[q*4+3] = -__expf(a.w) * 1.44269504f;
        }
    }
    float h[16];
    {
        const float4* Hv = (const float4*)(H_in + (((size_t)(b * NC + c) * DIN) + d) * 16);
        #pragma unroll
        for (int q = 0; q < 4; q++) {
            float4 v = Hv[q];
            h[q*4+0]=v.x; h[q*4+1]=v.y; h[q*4+2]=v.z; h[q*4+3]=v.w;
        }
    }
    const float Dpd = Dp[d];
    const int rowbase = b * L_SEQ + c * CL;
    #pragma unroll 2
    for (int t = 0; t < CL; ++t) {
        const int rowg = rowbase + t;
        const float dt = delta[rowg];
        const float4* Bv = (const float4*)(Bm + (size_t)rowg * 16);
        const float4* Cv = (const float4*)(Cm + (size_t)rowg * 16);
        float4 b0 = Bv[0], b1 = Bv[1], b2 = Bv[2], b3 = Bv[3];
        float4 c0 = Cv[0], c1 = Cv[1], c2 = Cv[2], c3 = Cv[3];
        float bb[16] = {b0.x,b0.y,b0.z,b0.w, b1.x,b1.y,b1.z,b1.w,
                        b2.x,b2.y,b2.z,b2.w, b3.x,b3.y,b3.z,b3.w};
        float cc[16] = {c0.x,c0.y,c0.z,c0.w, c1.x,c1.y,c1.z,c1.w,
                        c2.x,c2.y,c2.z,c2.w, c3.x,c3.y,c3.z,c3.w};
        const float xt = h2f(xc16[(size_t)rowg * DIN + d]);
        const float rt = h2f(res16[(size_t)rowg * DIN + d]);
        const float dtx = dt * xt;
        float y = 0.f;
        #pragma unroll
        for (int n = 0; n < 16; n++) {
            float a = fexp2(dt * ka[n]);
            h[n] = fmaf(a, h[n], bb[n] * dtx);
            y = fmaf(cc[n], h[n], y);
        }
        y = (y + xt * Dpd) * rt;
        yh[(size_t)rowg * DIN + d] = f2h_bits(y);
    }
}

extern "C" void kernel_launch(void* const* d_in, const int* in_sizes, int n_in,
                              void* d_out, int out_size, void* d_ws, size_t ws_size,
                              hipStream_t stream)
{
    const float* x     = (const float*)d_in[0];
    const float* W_in  = (const float*)d_in[1];
    const float* cw    = (const float*)d_in[2];
    const float* cb    = (const float*)d_in[3];
    const float* Wx    = (const float*)d_in[4];
    const float* A_log = (const float*)d_in[5];
    const float* Dp    = (const float*)d_in[6];
    const float* W_out = (const float*)d_in[7];
    float* out = (float*)d_out;
    float* ws  = (float*)d_ws;

    // workspace (float slot offsets); aliases valid by stream-order lifetimes
    u16*   xin16 = (u16*)(ws);                     // [4096][2048] ; dead after conv
    u16*   y16   = (u16*)(ws);                     // alias
    u16*   res16 = (u16*)(ws + 4194304);           // [4096][2048]
    u16*   xc16  = (u16*)(ws + 8388608);           // [4096][2048]
    u16*   x16   = (u16*)(ws + 12582912);          // [4096][1024] ; dead after GEMM1
    u16*   p2    = (u16*)(ws + 12582912);          // [2][4096][1024] (alias x16+Bt1)
    u16*   Bt1   = (u16*)(ws + 14680064);          // [4096][1024] ; dead after GEMM1
    float* pb    = ws + 14680064;                  // [8][4096][48] f32 (dead before GEMM3)
    u16*   WxT16 = (u16*)(ws + 20971520);          // [48][2048]
    float* delta = ws + 21020672;                  // 4096
    float* Bm    = ws + 21024768;                  // 65536
    float* Cm    = ws + 21090304;                  // 65536
    float* h_loc = ws + 21155840;                  // 2097152
    float* Pc    = ws + 23252992;                  // 2097152
    float* H_in  = ws + 25350144;                  // 2097152
    u16*   Bt3   = (u16*)(ws + 27447296);          // [1024][2048] (end 28495872 fl = 114 MB)

    dim3 blk(256), blk512(512);

    // 1) fused preprocessing
    prep_inputs<<<dim3(6016), blk, 0, stream>>>(x, W_in, W_out, Wx, x16, Bt1, Bt3, WxT16);
    // 2) GEMM1 (4-phase 256^2, round-10 config): xin16 | silu(res)16
    gemm8<1><<<dim3(16, 16, 1), blk512, 0, stream>>>(x16, Bt1, xin16, res16,
                                                     NROWS, 2 * DIN, DMOD, DMOD, DMOD);
    // 3) conv + bias + silu (LDS-tiled)
    conv_silu16t<<<dim3(DIN / 128, L_SEQ / 32, NB), blk, 0, stream>>>(xin16, cw, cb, xc16);
    // 4) ssm params
    gemm2_mfma<<<dim3(NROWS / 64, 8), blk, 0, stream>>>(xc16, WxT16, pb);
    gemm2_reduce<<<dim3(NROWS * 48 / 256), blk, 0, stream>>>(pb, delta, Bm, Cm);
    // 5) chunk-parallel scan
    scan_part1_reg<<<dim3(DIN / 256, NC, NB), blk, 0, stream>>>(xc16, delta, Bm, A_log, h_loc, Pc);
    scan_carry<<<dim3(NB * DIN * NST / 256), blk, 0, stream>>>(h_loc, Pc, H_in);
    scan_part3_reg<<<dim3(DIN / 256, NC, NB), blk, 0, stream>>>(xc16, delta, Bm, Cm, A_log, Dp, res16, H_in, y16);
    // 6) GEMM3 (gemm128c, split-K=2): grid (8,32,2) = 512 blocks, 2/CU, counted vmcnt(8)
    gemm128c<<<dim3(DMOD / 128, NROWS / 128, 2), blk, 0, stream>>>(y16, Bt3, p2,
                                                                   NROWS, DMOD, DIN / 2, DIN, DIN);
    // 7) out = p[0] + p[1] (fp32)
    add_partials<<<dim3(NROWS * DMOD / 8 / 256), blk, 0, stream>>>(p2, out);
}

// Round 13
// 180.686 us; speedup vs baseline: 1.1291x; 1.0358x over previous
//
#include <hip/hip_runtime.h>

#define L_SEQ 2048
#define NB    2
#define DMOD  1024
#define DIN   2048
#define NST   16
#define NROWS (NB*L_SEQ)   // 4096
#define CL    64
#define NC    (L_SEQ/CL)   // 32

typedef unsigned short u16;
typedef _Float16 half8 __attribute__((ext_vector_type(8)));
typedef float f32x4 __attribute__((ext_vector_type(4)));
typedef short short8 __attribute__((ext_vector_type(8)));

__device__ __forceinline__ float siluf(float v){ return v / (1.f + __expf(-v)); }
__device__ __forceinline__ u16 f2h_bits(float v){ _Float16 h = (_Float16)v; return __builtin_bit_cast(u16, h); }
__device__ __forceinline__ float h2f(u16 v){ return (float)__builtin_bit_cast(_Float16, v); }
__device__ __forceinline__ float fexp2(float x){
#if __has_builtin(__builtin_amdgcn_exp2f)
    return __builtin_amdgcn_exp2f(x);
#else
    return __expf(x * 0.69314718056f);
#endif
}

// async global->LDS, 16B per lane; lds base wave-uniform; dest = base + lane*16
__device__ __forceinline__ void gload16(const u16* g, u16* l)
{
    __builtin_amdgcn_global_load_lds(
        (const __attribute__((address_space(1))) void*)g,
        (__attribute__((address_space(3))) void*)l,
        16, 0, 0);
}

#define BARRIER() do { asm volatile("" ::: "memory"); __builtin_amdgcn_s_barrier(); asm volatile("" ::: "memory"); } while (0)
#define VMCNT0()  asm volatile("s_waitcnt vmcnt(0)" ::: "memory")
#define VMCNT2()  asm volatile("s_waitcnt vmcnt(2)" ::: "memory")
#define VMCNT8()  asm volatile("s_waitcnt vmcnt(8)" ::: "memory")

// ---------------- fused input preprocessing ----------------
__global__ __launch_bounds__(256)
void prep_inputs(const float* __restrict__ x, const float* __restrict__ W_in,
                 const float* __restrict__ W_out, const float* __restrict__ Wx,
                 u16* __restrict__ x16, u16* __restrict__ Bt1,
                 u16* __restrict__ Bt3, u16* __restrict__ WxT16)
{
    __shared__ float s[64][65];
    const int bid = blockIdx.x, tid = threadIdx.x;
    if (bid < 4096) {
        int i = bid * 256 + tid;                   // over NROWS*DMOD/4
        float4 v = ((const float4*)x)[i];
        ushort4 o;
        o.x = f2h_bits(v.x); o.y = f2h_bits(v.y); o.z = f2h_bits(v.z); o.w = f2h_bits(v.w);
        *(ushort4*)&x16[(size_t)i * 4] = o;
    } else if (bid < 5632) {
        const float* in; u16* outT; int R, C, rblk, cblk;
        if (bid < 5120) { int b = bid - 4096; in = W_in;  outT = Bt1; R = 1024; C = 4096; cblk = b & 63; rblk = b >> 6; }
        else            { int b = bid - 5120; in = W_out; outT = Bt3; R = 2048; C = 1024; cblk = b & 15; rblk = b >> 4; }
        int r0 = rblk * 64, c0 = cblk * 64;
        int tc = tid & 63, ty = tid >> 6;
        #pragma unroll
        for (int j = 0; j < 16; j++) {
            int r = ty + j * 4;
            s[r][tc] = in[(size_t)(r0 + r) * C + c0 + tc];
        }
        __syncthreads();
        #pragma unroll
        for (int j = 0; j < 16; j++) {
            int nn = ty + j * 4;
            outT[(size_t)(c0 + nn) * R + r0 + tc] = f2h_bits(s[tc][nn]);
        }
    } else {
        int idx = (bid - 5632) * 256 + tid;        // 48*2048
        int n = idx >> 11, k = idx & 2047;
        float v = (n < 33) ? Wx[k * 33 + n] : 0.f;
        WxT16[idx] = f2h_bits(v);
    }
}

// ---------------- 4-phase MFMA GEMM: 256x256 tile, BK=64, 8 waves, 512 thr ----------
// EPI==1: split N at half: col<half -> C0h (u16) ; else C1h = silu (u16)
template<int EPI>
__global__ __launch_bounds__(512, 2)
void gemm8(const u16* __restrict__ A, const u16* __restrict__ Bt,
           void* __restrict__ C0v, void* __restrict__ C1v,
           int M, int N, int KLEN, int lda, int ldb)
{
    __shared__ __align__(16) u16 As[2 * 256 * 64];   // 64 KB (2 bufs)
    __shared__ __align__(16) u16 Bs[2 * 256 * 64];   // 64 KB
    const int tid  = threadIdx.x;
    const int lane = tid & 63;
    const int w    = tid >> 6;                 // 0..7
    const int wm   = w >> 2, wn = w & 3;       // 2 x 4 wave grid
    const int bm = blockIdx.y * 256, bn = blockIdx.x * 256;
    const int kBase = blockIdx.z * KLEN;

    const int srow8 = lane >> 3;
    const int sunit = (lane & 7) ^ srow8;
    const u16* Ag = A  + (size_t)(bm + srow8) * lda + kBase + sunit * 8;
    const u16* Bg = Bt + (size_t)(bn + srow8) * ldb + kBase + sunit * 8;
    const int rw = w * 16;

    const int fr  = lane & 15;
    const int sl0 = ((lane >> 4) ^ (fr & 7)) * 8;
    int aOffs[8], bOffs[4];
    #pragma unroll
    for (int mi = 0; mi < 8; mi++) aOffs[mi] = (wm * 128 + mi * 16 + fr) * 64 + sl0;
    #pragma unroll
    for (int ni = 0; ni < 4; ni++) bOffs[ni] = (ni * 64 + wn * 16 + fr) * 64 + sl0;

    f32x4 acc[8][4];
    #pragma unroll
    for (int i = 0; i < 8; i++)
        #pragma unroll
        for (int j = 0; j < 4; j++)
            acc[i][j] = (f32x4){0.f, 0.f, 0.f, 0.f};

    auto stage2 = [&](const u16* G, int ld, int rbase, int kcol, u16* ldsDst) {
        gload16(G + (size_t)rbase * ld + kcol, ldsDst);
        gload16(G + (size_t)(rbase + 8) * ld + kcol, ldsDst + 8 * 64);
    };

    const int NT = KLEN >> 6;
    stage2(Ag, lda, 0 + rw, 0, &As[(0 + rw) * 64]);
    stage2(Ag, lda, 128 + rw, 0, &As[(128 + rw) * 64]);
    stage2(Bg, ldb, 0 + rw, 0, &Bs[(0 + rw) * 64]);
    stage2(Bg, ldb, 128 + rw, 0, &Bs[(128 + rw) * 64]);
    VMCNT2();
    BARRIER();

    for (int t = 0; t < NT; ++t) {
        const int cO = (t & 1) << 14;
        const int nO = cO ^ 16384;
        const int kn = (t + 1) << 6;
        const bool pf = (t + 1) < NT;
        half8 af[8], bf0, bf1;

        // ---- phase 0
        #pragma unroll
        for (int mi = 0; mi < 8; mi++) af[mi] = *(const half8*)&As[cO + aOffs[mi]];
        bf0 = *(const half8*)&Bs[cO + bOffs[0]];
        bf1 = *(const half8*)&Bs[cO + bOffs[1]];
        if (pf) stage2(Ag, lda, 0 + rw, kn, &As[nO + (0 + rw) * 64]);
        BARRIER();
        #pragma unroll
        for (int mi = 0; mi < 8; mi++) acc[mi][0] = __builtin_amdgcn_mfma_f32_16x16x32_f16(af[mi], bf0, acc[mi][0], 0, 0, 0);
        #pragma unroll
        for (int mi = 0; mi < 8; mi++) acc[mi][1] = __builtin_amdgcn_mfma_f32_16x16x32_f16(af[mi], bf1, acc[mi][1], 0, 0, 0);
        VMCNT2();
        BARRIER();

        // ---- phase 1
        bf0 = *(const half8*)&Bs[cO + bOffs[2]];
        bf1 = *(const half8*)&Bs[cO + bOffs[3]];
        if (pf) stage2(Ag, lda, 128 + rw, kn, &As[nO + (128 + rw) * 64]);
        BARRIER();
        #pragma unroll
        for (int mi = 0; mi < 8; mi++) acc[mi][2] = __builtin_amdgcn_mfma_f32_16x16x32_f16(af[mi], bf0, acc[mi][2], 0, 0, 0);
        #pragma unroll
        for (int mi = 0; mi < 8; mi++) acc[mi][3] = __builtin_amdgcn_mfma_f32_16x16x32_f16(af[mi], bf1, acc[mi][3], 0, 0, 0);
        BARRIER();

        // ---- phase 2
        #pragma unroll
        for (int mi = 0; mi < 8; mi++) af[mi] = *(const half8*)&As[cO + (aOffs[mi] ^ 32)];
        bf0 = *(const half8*)&Bs[cO + (bOffs[0] ^ 32)];
        bf1 = *(const half8*)&Bs[cO + (bOffs[1] ^ 32)];
        if (pf) stage2(Bg, ldb, 0 + rw, kn, &Bs[nO + (0 + rw) * 64]);
        BARRIER();
        #pragma unroll
        for (int mi = 0; mi < 8; mi++) acc[mi][0] = __builtin_amdgcn_mfma_f32_16x16x32_f16(af[mi], bf0, acc[mi][0], 0, 0, 0);
        #pragma unroll
        for (int mi = 0; mi < 8; mi++) acc[mi][1] = __builtin_amdgcn_mfma_f32_16x16x32_f16(af[mi], bf1, acc[mi][1], 0, 0, 0);
        BARRIER();

        // ---- phase 3
        bf0 = *(const half8*)&Bs[cO + (bOffs[2] ^ 32)];
        bf1 = *(const half8*)&Bs[cO + (bOffs[3] ^ 32)];
        if (pf) stage2(Bg, ldb, 128 + rw, kn, &Bs[nO + (128 + rw) * 64]);
        BARRIER();
        #pragma unroll
        for (int mi = 0; mi < 8; mi++) acc[mi][2] = __builtin_amdgcn_mfma_f32_16x16x32_f16(af[mi], bf0, acc[mi][2], 0, 0, 0);
        #pragma unroll
        for (int mi = 0; mi < 8; mi++) acc[mi][3] = __builtin_amdgcn_mfma_f32_16x16x32_f16(af[mi], bf1, acc[mi][3], 0, 0, 0);
        VMCNT2();
        BARRIER();
    }

    const int cr = (lane >> 4) * 4;
    #pragma unroll
    for (int mi = 0; mi < 8; mi++) {
        #pragma unroll
        for (int ni = 0; ni < 4; ni++) {
            #pragma unroll
            for (int q = 0; q < 4; q++) {
                int row = bm + wm * 128 + mi * 16 + cr + q;
                int col = bn + ni * 64 + wn * 16 + fr;
                float v = acc[mi][ni][q];
                int half = N >> 1;
                if (col < half) ((u16*)C0v)[(size_t)row * half + col] = f2h_bits(v);
                else            ((u16*)C1v)[(size_t)row * half + col - half] = f2h_bits(siluf(v));
            }
        }
    }
}

// ---------------- gemm128c: 128x128, BK=64, 4 waves, dbuf, counted vmcnt(8) ----
__global__ __launch_bounds__(256, 2)
void gemm128c(const u16* __restrict__ A, const u16* __restrict__ Bt,
              u16* __restrict__ C0, int M, int N, int KLEN, int lda, int ldb)
{
    __shared__ __align__(16) u16 As[2 * 128 * 64];   // 32 KB
    __shared__ __align__(16) u16 Bs[2 * 128 * 64];   // 32 KB
    const int tid  = threadIdx.x;
    const int lane = tid & 63;
    const int wid  = tid >> 6;
    const int wm   = wid >> 1, wn = wid & 1;
    const int bm = blockIdx.y * 128, bn = blockIdx.x * 128;
    const int kBase = blockIdx.z * KLEN;

    const int srow8 = lane >> 3;
    const int sunit = (lane & 7) ^ srow8;
    const u16* Ag = A  + (size_t)(bm + srow8) * lda + kBase + sunit * 8;
    const u16* Bg = Bt + (size_t)(bn + srow8) * ldb + kBase + sunit * 8;

    const int fr = lane & 15;
    const int s0 = ((lane >> 4) ^ (lane & 7)) * 8;
    const int aBase = (wm * 64 + fr) * 64 + s0;
    const int bBase = (wn * 64 + fr) * 64 + s0;

    f32x4 acc[4][4];
    #pragma unroll
    for (int i = 0; i < 4; i++)
        #pragma unroll
        for (int j = 0; j < 4; j++)
            acc[i][j] = (f32x4){0.f, 0.f, 0.f, 0.f};

    auto STAGE = [&](int bufO, int k0) {
        #pragma unroll
        for (int j = 0; j < 4; j++) {
            int c = wid * 4 + j;
            gload16(Ag + (size_t)(c * 8) * lda + k0, &As[bufO + c * 512]);
            gload16(Bg + (size_t)(c * 8) * ldb + k0, &Bs[bufO + c * 512]);
        }
    };

    auto COMPUTE = [&](int bufO) {
        #pragma unroll
        for (int kk = 0; kk < 2; kk++) {
            const int x = kk ? 32 : 0;
            half8 af[4], bf[4];
            #pragma unroll
            for (int mi = 0; mi < 4; mi++)
                af[mi] = *(const half8*)&As[bufO + (aBase ^ x) + mi * 1024];
            #pragma unroll
            for (int ni = 0; ni < 4; ni++)
                bf[ni] = *(const half8*)&Bs[bufO + (bBase ^ x) + ni * 1024];
            #pragma unroll
            for (int mi = 0; mi < 4; mi++)
                #pragma unroll
                for (int ni = 0; ni < 4; ni++)
                    acc[mi][ni] = __builtin_amdgcn_mfma_f32_16x16x32_f16(af[mi], bf[ni], acc[mi][ni], 0, 0, 0);
        }
    };

    const int NT = KLEN >> 6;                          // 16
    STAGE(0, 0);
    int buf = 0;
    for (int t = 0; t < NT; ++t) {
        if (t + 1 < NT) { STAGE(buf ^ 8192, (t + 1) << 6); VMCNT8(); }
        else            { VMCNT0(); }
        BARRIER();
        COMPUTE(buf);
        BARRIER();
        buf ^= 8192;
    }

    const int cr = (lane >> 4) * 4;
    const int cc = lane & 15;
    #pragma unroll
    for (int mi = 0; mi < 4; mi++) {
        #pragma unroll
        for (int ni = 0; ni < 4; ni++) {
            #pragma unroll
            for (int q = 0; q < 4; q++) {
                int row = bm + wm * 64 + mi * 16 + cr + q;
                int col = bn + wn * 64 + ni * 16 + cc;
                C0[((size_t)blockIdx.z * M + row) * N + col] = f2h_bits(acc[mi][ni][q]);
            }
        }
    }
}

// ---------------- sum the two split-K f16 partials -> fp32 out ----------------
__global__ __launch_bounds__(256)
void add_partials(const u16* __restrict__ p, float* __restrict__ out)
{
    int i = blockIdx.x * 256 + threadIdx.x;        // over 4096*1024/8
    short8 a = *(const short8*)&p[(size_t)i * 8];
    short8 b = *(const short8*)&p[(size_t)NROWS * DMOD + (size_t)i * 8];
    float4 o0, o1;
    o0.x = h2f((u16)a[0]) + h2f((u16)b[0]);
    o0.y = h2f((u16)a[1]) + h2f((u16)b[1]);
    o0.z = h2f((u16)a[2]) + h2f((u16)b[2]);
    o0.w = h2f((u16)a[3]) + h2f((u16)b[3]);
    o1.x = h2f((u16)a[4]) + h2f((u16)b[4]);
    o1.y = h2f((u16)a[5]) + h2f((u16)b[5]);
    o1.z = h2f((u16)a[6]) + h2f((u16)b[6]);
    o1.w = h2f((u16)a[7]) + h2f((u16)b[7]);
    *(float4*)&out[(size_t)i * 8]     = o0;
    *(float4*)&out[(size_t)i * 8 + 4] = o1;
}

// ---------------- depthwise causal conv + bias + SiLU, LDS-tiled ----------------
__global__ __launch_bounds__(256)
void conv_silu16t(const u16* __restrict__ xin16, const float* __restrict__ cw,
                  const float* __restrict__ cb, u16* __restrict__ xc16)
{
    __shared__ u16 sx[35][136];
    const int d0 = blockIdx.x << 7, t0 = blockIdx.y << 5, b = blockIdx.z;
    const int tid = threadIdx.x;
    for (int i = tid; i < 35 * 16; i += 256) {
        int r = i >> 4, u = i & 15;
        int t = t0 - 3 + r;
        short8 v = {0,0,0,0,0,0,0,0};
        if (t >= 0) v = *(const short8*)&xin16[((size_t)(b * L_SEQ + t)) * DIN + d0 + u * 8];
        *(short8*)&sx[r][u * 8] = v;
    }
    __syncthreads();
    const int u  = tid & 15;
    const int tl = tid >> 4;
    const int d  = d0 + u * 8;
    const float4* cw4 = (const float4*)cw;
    float4 w[8];
    #pragma unroll
    for (int j = 0; j < 8; j++) w[j] = cw4[d + j];
    float bias[8];
    {
        float4 b0 = *(const float4*)&cb[d];
        float4 b1 = *(const float4*)&cb[d + 4];
        bias[0]=b0.x; bias[1]=b0.y; bias[2]=b0.z; bias[3]=b0.w;
        bias[4]=b1.x; bias[5]=b1.y; bias[6]=b1.z; bias[7]=b1.w;
    }
    #pragma unroll
    for (int half = 0; half < 2; half++) {
        const int t_l = tl + half * 16;
        float acc[8];
        #pragma unroll
        for (int j = 0; j < 8; j++) acc[j] = bias[j];
        #pragma unroll
        for (int k = 0; k < 4; k++) {
            short8 v = *(const short8*)&sx[t_l + k][u * 8];
            #pragma unroll
            for (int j = 0; j < 8; j++)
                acc[j] = fmaf(h2f((u16)v[j]), (&w[j].x)[k], acc[j]);
        }
        short8 o;
        #pragma unroll
        for (int j = 0; j < 8; j++) o[j] = (short)f2h_bits(siluf(acc[j]));
        *(short8*)&xc16[((size_t)(b * L_SEQ + t0 + t_l)) * DIN + d] = o;
    }
}

// ---------------- GEMM2: [4096][2048] @ [48][2048]^T, K-split 8, tile M=64 ----------------
__global__ __launch_bounds__(256)
void gemm2_mfma(const u16* __restrict__ A, const u16* __restrict__ Bt, float* __restrict__ pb)
{
    __shared__ __align__(16) u16 As[64 * 64];
    __shared__ __align__(16) u16 Bs[48 * 64];
    const int tid = threadIdx.x, lane = tid & 63, w = tid >> 6;
    const int bm = blockIdx.x * 64;
    const int kz = blockIdx.y;
    const int arow = tid >> 2;
    const int au   = (tid & 3) << 1;
    f32x4 acc[3];
    acc[0] = acc[1] = acc[2] = (f32x4){0.f, 0.f, 0.f, 0.f};

    for (int it = 0; it < 4; ++it) {
        const int k0 = kz * 256 + it * 64;
        short8 ra0 = *(const short8*)&A[(size_t)(bm + arow) * DIN + k0 + au * 8];
        short8 ra1 = *(const short8*)&A[(size_t)(bm + arow) * DIN + k0 + (au + 1) * 8];
        short8 rb0, rb1;
        if (tid < 192) {
            rb0 = *(const short8*)&Bt[(size_t)arow * DIN + k0 + au * 8];
            rb1 = *(const short8*)&Bt[(size_t)arow * DIN + k0 + (au + 1) * 8];
        }
        __syncthreads();
        {
            int s0 = au ^ (arow & 7), s1 = (au + 1) ^ (arow & 7);
            *(short8*)&As[arow * 64 + s0 * 8] = ra0;
            *(short8*)&As[arow * 64 + s1 * 8] = ra1;
            if (tid < 192) {
                *(short8*)&Bs[arow * 64 + s0 * 8] = rb0;
                *(short8*)&Bs[arow * 64 + s1 * 8] = rb1;
            }
        }
        __syncthreads();
        #pragma unroll
        for (int kk = 0; kk < 2; kk++) {
            int r = w * 16 + (lane & 15);
            int sl = (kk * 4 + (lane >> 4)) ^ (r & 7);
            half8 af = *(const half8*)&As[r * 64 + sl * 8];
            #pragma unroll
            for (int ni = 0; ni < 3; ni++) {
                int br = ni * 16 + (lane & 15);
                int bsl = (kk * 4 + (lane >> 4)) ^ (br & 7);
                half8 bf = *(const half8*)&Bs[br * 64 + bsl * 8];
                acc[ni] = __builtin_amdgcn_mfma_f32_16x16x32_f16(af, bf, acc[ni], 0, 0, 0);
            }
        }
    }
    #pragma unroll
    for (int ni = 0; ni < 3; ni++) {
        #pragma unroll
        for (int q = 0; q < 4; q++) {
            int row = bm + w * 16 + (lane >> 4) * 4 + q;
            int col = ni * 16 + (lane & 15);
            pb[((size_t)kz * NROWS + row) * 48 + col] = acc[ni][q];
        }
    }
}

// ---------------- GEMM2 reduce: sum 8 partials, softplus col0, split B/C ----------------
__global__ __launch_bounds__(256)
void gemm2_reduce(const float* __restrict__ pb, float* __restrict__ delta,
                  float* __restrict__ Bm, float* __restrict__ Cm)
{
    int idx = blockIdx.x * 256 + threadIdx.x;      // 4096*48
    int row = idx / 48, col = idx - row * 48;
    float s = 0.f;
    #pragma unroll
    for (int kz = 0; kz < 8; kz++) s += pb[(size_t)kz * NROWS * 48 + idx];
    if (col == 0)       delta[row] = fmaxf(s, 0.f) + log1pf(__expf(-fabsf(s)));
    else if (col < 17)  Bm[row * NST + col - 1]  = s;
    else if (col < 33)  Cm[row * NST + col - 17] = s;
}

// ---------------- scan pass 1: thread-per-d, h[16] in regs; h -> f16, S per chunk ----
__global__ __launch_bounds__(256)
void scan_part1_reg(const u16* __restrict__ xc16, const float* __restrict__ delta,
                    const float* __restrict__ Bm, const float* __restrict__ A_log,
                    u16* __restrict__ h16, float* __restrict__ Sc)
{
    const int b = blockIdx.z, c = blockIdx.y;
    const int d = blockIdx.x * 256 + threadIdx.x;
    float ka[16];
    {
        const float4* Av = (const float4*)(A_log + (size_t)d * 16);
        #pragma unroll
        for (int q = 0; q < 4; q++) {
            float4 a = Av[q];
            ka[q*4+0] = -__expf(a.x) * 1.44269504f;
            ka[q*4+1] = -__expf(a.y) * 1.44269504f;
            ka[q*4+2] = -__expf(a.z) * 1.44269504f;
            ka[q*4+3] = -__expf(a.w) * 1.44269504f;
        }
    }
    float h[16];
    #pragma unroll
    for (int n = 0; n < 16; n++) h[n] = 0.f;
    float S = 0.f;
    const int rowbase = b * L_SEQ + c * CL;
    #pragma unroll 2
    for (int t = 0; t < CL; ++t) {
        const int rowg = rowbase + t;
        const float dt = delta[rowg];
        const float4* Bv = (const float4*)(Bm + (size_t)rowg * 16);
        float4 b0 = Bv[0], b1 = Bv[1], b2 = Bv[2], b3 = Bv[3];
        float bb[16] = {b0.x,b0.y,b0.z,b0.w, b1.x,b1.y,b1.z,b1.w,
                        b2.x,b2.y,b2.z,b2.w, b3.x,b3.y,b3.z,b3.w};
        const float xt = h2f(xc16[(size_t)rowg * DIN + d]);
        const float dtx = dt * xt;
        S += dt;
        #pragma unroll
        for (int n = 0; n < 16; n++) {
            float a = fexp2(dt * ka[n]);
            h[n] = fmaf(a, h[n], bb[n] * dtx);
        }
    }
    u16* hp = h16 + (((size_t)(b * NC + c) * DIN) + d) * 16;
    short8 o0, o1;
    #pragma unroll
    for (int j = 0; j < 8; j++) { o0[j] = (short)f2h_bits(h[j]); o1[j] = (short)f2h_bits(h[8 + j]); }
    *(short8*)&hp[0] = o0;
    *(short8*)&hp[8] = o1;
    if (threadIdx.x == 0 && blockIdx.x == 0) Sc[b * NC + c] = S;
}

// ---------------- scan pass 2: sequential carry across chunks (Pc recomputed) ----------
__global__ __launch_bounds__(256)
void scan_carry(const u16* __restrict__ h16, const float* __restrict__ Sc,
                const float* __restrict__ A_log, u16* __restrict__ H16)
{
    int gid = blockIdx.x * 256 + threadIdx.x;      // NB*DIN*NST = 65536
    int b = gid >> 15, r = gid & 32767;            // r = d*16 + n
    const float ka = -__expf(A_log[r]) * 1.44269504f;
    float H = 0.f;
    for (int c = 0; c < NC; ++c) {
        size_t idx = ((size_t)(b * NC + c) << 15) + r;
        H16[idx] = f2h_bits(H);
        float P = fexp2(Sc[b * NC + c] * ka);
        H = fmaf(P, H, h2f(h16[idx]));
    }
}

// ---------------- scan pass 3: thread-per-d, fused epilogue -> y fp16 ----------------
__global__ __launch_bounds__(256)
void scan_part3_reg(const u16* __restrict__ xc16, const float* __restrict__ delta,
                    const float* __restrict__ Bm, const float* __restrict__ Cm,
                    const float* __restrict__ A_log, const float* __restrict__ Dp,
                    const u16* __restrict__ res16, const u16* __restrict__ H16,
                    u16* __restrict__ yh)
{
    const int b = blockIdx.z, c = blockIdx.y;
    const int d = blockIdx.x * 256 + threadIdx.x;
    float ka[16];
    {
        const float4* Av = (const float4*)(A_log + (size_t)d * 16);
        #pragma unroll
        for (int q = 0; q < 4; q++) {
            float4 a = Av[q];
            ka[q*4+0] = -__expf(a.x) * 1.44269504f;
            ka[q*4+1] = -__expf(a.y) * 1.44269504f;
            ka[q*4+2] = -__expf(a.z) * 1.44269504f;
            ka[q*4+3] = -__expf(a.w) * 1.44269504f;
        }
    }
    float h[16];
    {
        const u16* Hp = H16 + (((size_t)(b * NC + c) * DIN) + d) * 16;
        short8 v0 = *(const short8*)&Hp[0];
        short8 v1 = *(const short8*)&Hp[8];
        #pragma unroll
        for (int j = 0; j < 8; j++) { h[j] = h2f((u16)v0[j]); h[8 + j] = h2f((u16)v1[j]); }
    }
    const float Dpd = Dp[d];
    const int rowbase = b * L_SEQ + c * CL;
    #pragma unroll 2
    for (int t = 0; t < CL; ++t) {
        const int rowg = rowbase + t;
        const float dt = delta[rowg];
        const float4* Bv = (const float4*)(Bm + (size_t)rowg * 16);
        const float4* Cv = (const float4*)(Cm + (size_t)rowg * 16);
        float4 b0 = Bv[0], b1 = Bv[1], b2 = Bv[2], b3 = Bv[3];
        float4 c0 = Cv[0], c1 = Cv[1], c2 = Cv[2], c3 = Cv[3];
        float bb[16] = {b0.x,b0.y,b0.z,b0.w, b1.x,b1.y,b1.z,b1.w,
                        b2.x,b2.y,b2.z,b2.w, b3.x,b3.y,b3.z,b3.w};
        float cc[16] = {c0.x,c0.y,c0.z,c0.w, c1.x,c1.y,c1.z,c1.w,
                        c2.x,c2.y,c2.z,c2.w, c3.x,c3.y,c3.z,c3.w};
        const float xt = h2f(xc16[(size_t)rowg * DIN + d]);
        const float rt = h2f(res16[(size_t)rowg * DIN + d]);
        const float dtx = dt * xt;
        float y = 0.f;
        #pragma unroll
        for (int n = 0; n < 16; n++) {
            float a = fexp2(dt * ka[n]);
            h[n] = fmaf(a, h[n], bb[n] * dtx);
            y = fmaf(cc[n], h[n], y);
        }
        y = (y + xt * Dpd) * rt;
        yh[(size_t)rowg * DIN + d] = f2h_bits(y);
    }
}

extern "C" void kernel_launch(void* const* d_in, const int* in_sizes, int n_in,
                              void* d_out, int out_size, void* d_ws, size_t ws_size,
                              hipStream_t stream)
{
    const float* x     = (const float*)d_in[0];
    const float* W_in  = (const float*)d_in[1];
    const float* cw    = (const float*)d_in[2];
    const float* cb    = (const float*)d_in[3];
    const float* Wx    = (const float*)d_in[4];
    const float* A_log = (const float*)d_in[5];
    const float* Dp    = (const float*)d_in[6];
    const float* W_out = (const float*)d_in[7];
    float* out = (float*)d_out;
    float* ws  = (float*)d_ws;

    // workspace (float slot offsets); aliases valid by stream-order lifetimes
    u16*   xin16 = (u16*)(ws);                     // [4096][2048] ; dead after conv
    u16*   y16   = (u16*)(ws);                     // alias
    u16*   res16 = (u16*)(ws + 4194304);           // [4096][2048]
    u16*   xc16  = (u16*)(ws + 8388608);           // [4096][2048]
    u16*   x16   = (u16*)(ws + 12582912);          // [4096][1024] ; dead after GEMM1
    u16*   p2    = (u16*)(ws + 12582912);          // [2][4096][1024] (alias x16+Bt1)
    u16*   Bt1   = (u16*)(ws + 14680064);          // [4096][1024] ; dead after GEMM1
    float* pb    = ws + 14680064;                  // [8][4096][48] f32 (dead before GEMM3)
    u16*   WxT16 = (u16*)(ws + 20971520);          // [48][2048]
    float* delta = ws + 21020672;                  // 4096
    float* Bm    = ws + 21024768;                  // 65536
    float* Cm    = ws + 21090304;                  // 65536
    float* Sc    = ws + 21155840;                  // 64 (padded to 1024)
    u16*   h16   = (u16*)(ws + 21156864);          // [NB*NC][DIN][16] u16 = 1048576 fl
    u16*   H16   = (u16*)(ws + 22205440);          // same size
    u16*   Bt3   = (u16*)(ws + 23254016);          // [1024][2048] (end 24302592 fl = 97 MB)

    dim3 blk(256), blk512(512);

    // 1) fused preprocessing
    prep_inputs<<<dim3(6016), blk, 0, stream>>>(x, W_in, W_out, Wx, x16, Bt1, Bt3, WxT16);
    // 2) GEMM1 (4-phase 256^2): xin16 | silu(res)16
    gemm8<1><<<dim3(16, 16, 1), blk512, 0, stream>>>(x16, Bt1, xin16, res16,
                                                     NROWS, 2 * DIN, DMOD, DMOD, DMOD);
    // 3) conv + bias + silu (LDS-tiled)
    conv_silu16t<<<dim3(DIN / 128, L_SEQ / 32, NB), blk, 0, stream>>>(xin16, cw, cb, xc16);
    // 4) ssm params
    gemm2_mfma<<<dim3(NROWS / 64, 8), blk, 0, stream>>>(xc16, WxT16, pb);
    gemm2_reduce<<<dim3(NROWS * 48 / 256), blk, 0, stream>>>(pb, delta, Bm, Cm);
    // 5) chunk-parallel scan (h/H fp16, Pc recomputed from S)
    scan_part1_reg<<<dim3(DIN / 256, NC, NB), blk, 0, stream>>>(xc16, delta, Bm, A_log, h16, Sc);
    scan_carry<<<dim3(NB * DIN * NST / 256), blk, 0, stream>>>(h16, Sc, A_log, H16);
    scan_part3_reg<<<dim3(DIN / 256, NC, NB), blk, 0, stream>>>(xc16, delta, Bm, Cm, A_log, Dp, res16, H16, y16);
    // 6) GEMM3 (gemm128c, split-K=2): grid (8,32,2) = 512 blocks, 2/CU, counted vmcnt(8)
    gemm128c<<<dim3(DMOD / 128, NROWS / 128, 2), blk, 0, stream>>>(y16, Bt3, p2,
                                                                   NROWS, DMOD, DIN / 2, DIN, DIN);
    // 7) out = p[0] + p[1] (fp32)
    add_partials<<<dim3(NROWS * DMOD / 8 / 256), blk, 0, stream>>>(p2, out);
}

// Round 14
// 178.328 us; speedup vs baseline: 1.1440x; 1.0132x over previous
//
#include <hip/hip_runtime.h>

#define L_SEQ 2048
#define NB    2
#define DMOD  1024
#define DIN   2048
#define NST   16
#define NROWS (NB*L_SEQ)   // 4096
#define CL    64
#define NC    (L_SEQ/CL)   // 32

typedef unsigned short u16;
typedef _Float16 half8 __attribute__((ext_vector_type(8)));
typedef float f32x4 __attribute__((ext_vector_type(4)));
typedef short short8 __attribute__((ext_vector_type(8)));

__device__ __forceinline__ float siluf(float v){ return v / (1.f + __expf(-v)); }
__device__ __forceinline__ u16 f2h_bits(float v){ _Float16 h = (_Float16)v; return __builtin_bit_cast(u16, h); }
__device__ __forceinline__ float h2f(u16 v){ return (float)__builtin_bit_cast(_Float16, v); }
__device__ __forceinline__ float fexp2(float x){
#if __has_builtin(__builtin_amdgcn_exp2f)
    return __builtin_amdgcn_exp2f(x);
#else
    return __expf(x * 0.69314718056f);
#endif
}

// async global->LDS, 16B per lane; lds base wave-uniform; dest = base + lane*16
__device__ __forceinline__ void gload16(const u16* g, u16* l)
{
    __builtin_amdgcn_global_load_lds(
        (const __attribute__((address_space(1))) void*)g,
        (__attribute__((address_space(3))) void*)l,
        16, 0, 0);
}

#define BARRIER() do { asm volatile("" ::: "memory"); __builtin_amdgcn_s_barrier(); asm volatile("" ::: "memory"); } while (0)
#define VMCNT0()  asm volatile("s_waitcnt vmcnt(0)" ::: "memory")
#define VMCNT2()  asm volatile("s_waitcnt vmcnt(2)" ::: "memory")
#define VMCNT4()  asm volatile("s_waitcnt vmcnt(4)" ::: "memory")
#define VMCNT8()  asm volatile("s_waitcnt vmcnt(8)" ::: "memory")

// ---------------- fused input preprocessing ----------------
__global__ __launch_bounds__(256)
void prep_inputs(const float* __restrict__ x, const float* __restrict__ W_in,
                 const float* __restrict__ W_out, const float* __restrict__ Wx,
                 u16* __restrict__ x16, u16* __restrict__ Bt1,
                 u16* __restrict__ Bt3, u16* __restrict__ WxT16)
{
    __shared__ float s[64][65];
    const int bid = blockIdx.x, tid = threadIdx.x;
    if (bid < 4096) {
        int i = bid * 256 + tid;                   // over NROWS*DMOD/4
        float4 v = ((const float4*)x)[i];
        ushort4 o;
        o.x = f2h_bits(v.x); o.y = f2h_bits(v.y); o.z = f2h_bits(v.z); o.w = f2h_bits(v.w);
        *(ushort4*)&x16[(size_t)i * 4] = o;
    } else if (bid < 5632) {
        const float* in; u16* outT; int R, C, rblk, cblk;
        if (bid < 5120) { int b = bid - 4096; in = W_in;  outT = Bt1; R = 1024; C = 4096; cblk = b & 63; rblk = b >> 6; }
        else            { int b = bid - 5120; in = W_out; outT = Bt3; R = 2048; C = 1024; cblk = b & 15; rblk = b >> 4; }
        int r0 = rblk * 64, c0 = cblk * 64;
        int tc = tid & 63, ty = tid >> 6;
        #pragma unroll
        for (int j = 0; j < 16; j++) {
            int r = ty + j * 4;
            s[r][tc] = in[(size_t)(r0 + r) * C + c0 + tc];
        }
        __syncthreads();
        #pragma unroll
        for (int j = 0; j < 16; j++) {
            int nn = ty + j * 4;
            outT[(size_t)(c0 + nn) * R + r0 + tc] = f2h_bits(s[tc][nn]);
        }
    } else {
        int idx = (bid - 5632) * 256 + tid;        // 48*2048
        int n = idx >> 11, k = idx & 2047;
        float v = (n < 33) ? Wx[k * 33 + n] : 0.f;
        WxT16[idx] = f2h_bits(v);
    }
}

// ---------------- gemm8b: 256x256 tile, BK=64, 8 waves, 2-phase / 2-barrier per K-tile --
// Hazard-minimal schedule: tile-top vmcnt(2)+barrier certifies A(t)+B-h0(t);
// mid-tile vmcnt(4)+barrier certifies B-h1(t). A fragments live in regs across phases.
// Stage: ph0 -> A(t+1) (4 gloads), ph1 -> B(t+1) (4 gloads). Outstanding: 8->2->6->4->8.
// EPI==1: split N at half: col<half -> C0h (u16) ; else C1h = silu (u16)
template<int EPI>
__global__ __launch_bounds__(512, 2)
void gemm8b(const u16* __restrict__ A, const u16* __restrict__ Bt,
            void* __restrict__ C0v, void* __restrict__ C1v,
            int M, int N, int KLEN, int lda, int ldb)
{
    __shared__ __align__(16) u16 As[2 * 256 * 64];   // 64 KB (2 bufs)
    __shared__ __align__(16) u16 Bs[2 * 256 * 64];   // 64 KB
    const int tid  = threadIdx.x;
    const int lane = tid & 63;
    const int w    = tid >> 6;                 // 0..7
    const int wm   = w >> 2, wn = w & 3;       // 2 x 4 wave grid
    const int bm = blockIdx.y * 256, bn = blockIdx.x * 256;
    const int kBase = blockIdx.z * KLEN;

    const int srow8 = lane >> 3;
    const int sunit = (lane & 7) ^ srow8;
    const u16* Ag = A  + (size_t)(bm + srow8) * lda + kBase + sunit * 8;
    const u16* Bg = Bt + (size_t)(bn + srow8) * ldb + kBase + sunit * 8;
    const int rw = w * 16;

    const int fr  = lane & 15;
    const int sl0 = ((lane >> 4) ^ (fr & 7)) * 8;
    int aOffs[8], bOffs[4];
    #pragma unroll
    for (int mi = 0; mi < 8; mi++) aOffs[mi] = (wm * 128 + mi * 16 + fr) * 64 + sl0;
    #pragma unroll
    for (int ni = 0; ni < 4; ni++) bOffs[ni] = (ni * 64 + wn * 16 + fr) * 64 + sl0;

    f32x4 acc[8][4];
    #pragma unroll
    for (int i = 0; i < 8; i++)
        #pragma unroll
        for (int j = 0; j < 4; j++)
            acc[i][j] = (f32x4){0.f, 0.f, 0.f, 0.f};

    auto stage2 = [&](const u16* G, int ld, int rbase, int kcol, u16* ldsDst) {
        gload16(G + (size_t)rbase * ld + kcol, ldsDst);
        gload16(G + (size_t)(rbase + 8) * ld + kcol, ldsDst + 8 * 64);
    };

    const int NT = KLEN >> 6;
    // prologue: stage tile 0 fully into buf 0 (A first, then B -> B-h1 newest)
    stage2(Ag, lda, 0 + rw, 0, &As[(0 + rw) * 64]);
    stage2(Ag, lda, 128 + rw, 0, &As[(128 + rw) * 64]);
    stage2(Bg, ldb, 0 + rw, 0, &Bs[(0 + rw) * 64]);
    stage2(Bg, ldb, 128 + rw, 0, &Bs[(128 + rw) * 64]);

    for (int t = 0; t < NT; ++t) {
        const int cO = (t & 1) << 14;
        const int nO = cO ^ 16384;
        const int kn = (t + 1) << 6;
        const bool pf = (t + 1) < NT;

        VMCNT2();          // own A(t)+B-h0(t) landed (B-h1(t) may still fly)
        BARRIER();         // all waves' A(t)+B-h0(t) visible; all prior-tile reads done

        half8 a0[8], a1[8];
        #pragma unroll
        for (int mi = 0; mi < 8; mi++) {
            a0[mi] = *(const half8*)&As[cO + aOffs[mi]];
            a1[mi] = *(const half8*)&As[cO + (aOffs[mi] ^ 32)];
        }
        half8 b00 = *(const half8*)&Bs[cO + bOffs[0]];
        half8 b01 = *(const half8*)&Bs[cO + (bOffs[0] ^ 32)];
        half8 b10 = *(const half8*)&Bs[cO + bOffs[1]];
        half8 b11 = *(const half8*)&Bs[cO + (bOffs[1] ^ 32)];
        if (pf) {
            stage2(Ag, lda, 0 + rw, kn, &As[nO + (0 + rw) * 64]);
            stage2(Ag, lda, 128 + rw, kn, &As[nO + (128 + rw) * 64]);
        }
        #pragma unroll
        for (int mi = 0; mi < 8; mi++) {
            acc[mi][0] = __builtin_amdgcn_mfma_f32_16x16x32_f16(a0[mi], b00, acc[mi][0], 0, 0, 0);
            acc[mi][0] = __builtin_amdgcn_mfma_f32_16x16x32_f16(a1[mi], b01, acc[mi][0], 0, 0, 0);
        }
        #pragma unroll
        for (int mi = 0; mi < 8; mi++) {
            acc[mi][1] = __builtin_amdgcn_mfma_f32_16x16x32_f16(a0[mi], b10, acc[mi][1], 0, 0, 0);
            acc[mi][1] = __builtin_amdgcn_mfma_f32_16x16x32_f16(a1[mi], b11, acc[mi][1], 0, 0, 0);
        }
        if (pf) VMCNT4(); else VMCNT0();   // B-h1(t) landed (A(t+1) may still fly)
        BARRIER();

        b00 = *(const half8*)&Bs[cO + bOffs[2]];
        b01 = *(const half8*)&Bs[cO + (bOffs[2] ^ 32)];
        b10 = *(const half8*)&Bs[cO + bOffs[3]];
        b11 = *(const half8*)&Bs[cO + (bOffs[3] ^ 32)];
        if (pf) {
            stage2(Bg, ldb, 0 + rw, kn, &Bs[nO + (0 + rw) * 64]);
            stage2(Bg, ldb, 128 + rw, kn, &Bs[nO + (128 + rw) * 64]);
        }
        #pragma unroll
        for (int mi = 0; mi < 8; mi++) {
            acc[mi][2] = __builtin_amdgcn_mfma_f32_16x16x32_f16(a0[mi], b00, acc[mi][2], 0, 0, 0);
            acc[mi][2] = __builtin_amdgcn_mfma_f32_16x16x32_f16(a1[mi], b01, acc[mi][2], 0, 0, 0);
        }
        #pragma unroll
        for (int mi = 0; mi < 8; mi++) {
            acc[mi][3] = __builtin_amdgcn_mfma_f32_16x16x32_f16(a0[mi], b10, acc[mi][3], 0, 0, 0);
            acc[mi][3] = __builtin_amdgcn_mfma_f32_16x16x32_f16(a1[mi], b11, acc[mi][3], 0, 0, 0);
        }
    }

    const int cr = (lane >> 4) * 4;
    #pragma unroll
    for (int mi = 0; mi < 8; mi++) {
        #pragma unroll
        for (int ni = 0; ni < 4; ni++) {
            #pragma unroll
            for (int q = 0; q < 4; q++) {
                int row = bm + wm * 128 + mi * 16 + cr + q;
                int col = bn + ni * 64 + wn * 16 + fr;
                float v = acc[mi][ni][q];
                int half = N >> 1;
                if (col < half) ((u16*)C0v)[(size_t)row * half + col] = f2h_bits(v);
                else            ((u16*)C1v)[(size_t)row * half + col - half] = f2h_bits(siluf(v));
            }
        }
    }
}

// ---------------- gemm128c: 128x128, BK=64, 4 waves, dbuf, counted vmcnt(8) ----
__global__ __launch_bounds__(256, 2)
void gemm128c(const u16* __restrict__ A, const u16* __restrict__ Bt,
              u16* __restrict__ C0, int M, int N, int KLEN, int lda, int ldb)
{
    __shared__ __align__(16) u16 As[2 * 128 * 64];   // 32 KB
    __shared__ __align__(16) u16 Bs[2 * 128 * 64];   // 32 KB
    const int tid  = threadIdx.x;
    const int lane = tid & 63;
    const int wid  = tid >> 6;
    const int wm   = wid >> 1, wn = wid & 1;
    const int bm = blockIdx.y * 128, bn = blockIdx.x * 128;
    const int kBase = blockIdx.z * KLEN;

    const int srow8 = lane >> 3;
    const int sunit = (lane & 7) ^ srow8;
    const u16* Ag = A  + (size_t)(bm + srow8) * lda + kBase + sunit * 8;
    const u16* Bg = Bt + (size_t)(bn + srow8) * ldb + kBase + sunit * 8;

    const int fr = lane & 15;
    const int s0 = ((lane >> 4) ^ (lane & 7)) * 8;
    const int aBase = (wm * 64 + fr) * 64 + s0;
    const int bBase = (wn * 64 + fr) * 64 + s0;

    f32x4 acc[4][4];
    #pragma unroll
    for (int i = 0; i < 4; i++)
        #pragma unroll
        for (int j = 0; j < 4; j++)
            acc[i][j] = (f32x4){0.f, 0.f, 0.f, 0.f};

    auto STAGE = [&](int bufO, int k0) {
        #pragma unroll
        for (int j = 0; j < 4; j++) {
            int c = wid * 4 + j;
            gload16(Ag + (size_t)(c * 8) * lda + k0, &As[bufO + c * 512]);
            gload16(Bg + (size_t)(c * 8) * ldb + k0, &Bs[bufO + c * 512]);
        }
    };

    auto COMPUTE = [&](int bufO) {
        #pragma unroll
        for (int kk = 0; kk < 2; kk++) {
            const int x = kk ? 32 : 0;
            half8 af[4], bf[4];
            #pragma unroll
            for (int mi = 0; mi < 4; mi++)
                af[mi] = *(const half8*)&As[bufO + (aBase ^ x) + mi * 1024];
            #pragma unroll
            for (int ni = 0; ni < 4; ni++)
                bf[ni] = *(const half8*)&Bs[bufO + (bBase ^ x) + ni * 1024];
            #pragma unroll
            for (int mi = 0; mi < 4; mi++)
                #pragma unroll
                for (int ni = 0; ni < 4; ni++)
                    acc[mi][ni] = __builtin_amdgcn_mfma_f32_16x16x32_f16(af[mi], bf[ni], acc[mi][ni], 0, 0, 0);
        }
    };

    const int NT = KLEN >> 6;                          // 16
    STAGE(0, 0);
    int buf = 0;
    for (int t = 0; t < NT; ++t) {
        if (t + 1 < NT) { STAGE(buf ^ 8192, (t + 1) << 6); VMCNT8(); }
        else            { VMCNT0(); }
        BARRIER();
        COMPUTE(buf);
        BARRIER();
        buf ^= 8192;
    }

    const int cr = (lane >> 4) * 4;
    const int cc = lane & 15;
    #pragma unroll
    for (int mi = 0; mi < 4; mi++) {
        #pragma unroll
        for (int ni = 0; ni < 4; ni++) {
            #pragma unroll
            for (int q = 0; q < 4; q++) {
                int row = bm + wm * 64 + mi * 16 + cr + q;
                int col = bn + wn * 64 + ni * 16 + cc;
                C0[((size_t)blockIdx.z * M + row) * N + col] = f2h_bits(acc[mi][ni][q]);
            }
        }
    }
}

// ---------------- sum the two split-K f16 partials -> fp32 out ----------------
__global__ __launch_bounds__(256)
void add_partials(const u16* __restrict__ p, float* __restrict__ out)
{
    int i = blockIdx.x * 256 + threadIdx.x;        // over 4096*1024/8
    short8 a = *(const short8*)&p[(size_t)i * 8];
    short8 b = *(const short8*)&p[(size_t)NROWS * DMOD + (size_t)i * 8];
    float4 o0, o1;
    o0.x = h2f((u16)a[0]) + h2f((u16)b[0]);
    o0.y = h2f((u16)a[1]) + h2f((u16)b[1]);
    o0.z = h2f((u16)a[2]) + h2f((u16)b[2]);
    o0.w = h2f((u16)a[3]) + h2f((u16)b[3]);
    o1.x = h2f((u16)a[4]) + h2f((u16)b[4]);
    o1.y = h2f((u16)a[5]) + h2f((u16)b[5]);
    o1.z = h2f((u16)a[6]) + h2f((u16)b[6]);
    o1.w = h2f((u16)a[7]) + h2f((u16)b[7]);
    *(float4*)&out[(size_t)i * 8]     = o0;
    *(float4*)&out[(size_t)i * 8 + 4] = o1;
}

// ---------------- depthwise causal conv + bias + SiLU, LDS-tiled ----------------
__global__ __launch_bounds__(256)
void conv_silu16t(const u16* __restrict__ xin16, const float* __restrict__ cw,
                  const float* __restrict__ cb, u16* __restrict__ xc16)
{
    __shared__ u16 sx[35][136];
    const int d0 = blockIdx.x << 7, t0 = blockIdx.y << 5, b = blockIdx.z;
    const int tid = threadIdx.x;
    for (int i = tid; i < 35 * 16; i += 256) {
        int r = i >> 4, u = i & 15;
        int t = t0 - 3 + r;
        short8 v = {0,0,0,0,0,0,0,0};
        if (t >= 0) v = *(const short8*)&xin16[((size_t)(b * L_SEQ + t)) * DIN + d0 + u * 8];
        *(short8*)&sx[r][u * 8] = v;
    }
    __syncthreads();
    const int u  = tid & 15;
    const int tl = tid >> 4;
    const int d  = d0 + u * 8;
    const float4* cw4 = (const float4*)cw;
    float4 w[8];
    #pragma unroll
    for (int j = 0; j < 8; j++) w[j] = cw4[d + j];
    float bias[8];
    {
        float4 b0 = *(const float4*)&cb[d];
        float4 b1 = *(const float4*)&cb[d + 4];
        bias[0]=b0.x; bias[1]=b0.y; bias[2]=b0.z; bias[3]=b0.w;
        bias[4]=b1.x; bias[5]=b1.y; bias[6]=b1.z; bias[7]=b1.w;
    }
    #pragma unroll
    for (int half = 0; half < 2; half++) {
        const int t_l = tl + half * 16;
        float acc[8];
        #pragma unroll
        for (int j = 0; j < 8; j++) acc[j] = bias[j];
        #pragma unroll
        for (int k = 0; k < 4; k++) {
            short8 v = *(const short8*)&sx[t_l + k][u * 8];
            #pragma unroll
            for (int j = 0; j < 8; j++)
                acc[j] = fmaf(h2f((u16)v[j]), (&w[j].x)[k], acc[j]);
        }
        short8 o;
        #pragma unroll
        for (int j = 0; j < 8; j++) o[j] = (short)f2h_bits(siluf(acc[j]));
        *(short8*)&xc16[((size_t)(b * L_SEQ + t0 + t_l)) * DIN + d] = o;
    }
}

// ---------------- GEMM2: [4096][2048] @ [48][2048]^T, K-split 8, tile M=64 ----------------
__global__ __launch_bounds__(256)
void gemm2_mfma(const u16* __restrict__ A, const u16* __restrict__ Bt, float* __restrict__ pb)
{
    __shared__ __align__(16) u16 As[64 * 64];
    __shared__ __align__(16) u16 Bs[48 * 64];
    const int tid = threadIdx.x, lane = tid & 63, w = tid >> 6;
    const int bm = blockIdx.x * 64;
    const int kz = blockIdx.y;
    const int arow = tid >> 2;
    const int au   = (tid & 3) << 1;
    f32x4 acc[3];
    acc[0] = acc[1] = acc[2] = (f32x4){0.f, 0.f, 0.f, 0.f};

    for (int it = 0; it < 4; ++it) {
        const int k0 = kz * 256 + it * 64;
        short8 ra0 = *(const short8*)&A[(size_t)(bm + arow) * DIN + k0 + au * 8];
        short8 ra1 = *(const short8*)&A[(size_t)(bm + arow) * DIN + k0 + (au + 1) * 8];
        short8 rb0, rb1;
        if (tid < 192) {
            rb0 = *(const short8*)&Bt[(size_t)arow * DIN + k0 + au * 8];
            rb1 = *(const short8*)&Bt[(size_t)arow * DIN + k0 + (au + 1) * 8];
        }
        __syncthreads();
        {
            int s0 = au ^ (arow & 7), s1 = (au + 1) ^ (arow & 7);
            *(short8*)&As[arow * 64 + s0 * 8] = ra0;
            *(short8*)&As[arow * 64 + s1 * 8] = ra1;
            if (tid < 192) {
                *(short8*)&Bs[arow * 64 + s0 * 8] = rb0;
                *(short8*)&Bs[arow * 64 + s1 * 8] = rb1;
            }
        }
        __syncthreads();
        #pragma unroll
        for (int kk = 0; kk < 2; kk++) {
            int r = w * 16 + (lane & 15);
            int sl = (kk * 4 + (lane >> 4)) ^ (r & 7);
            half8 af = *(const half8*)&As[r * 64 + sl * 8];
            #pragma unroll
            for (int ni = 0; ni < 3; ni++) {
                int br = ni * 16 + (lane & 15);
                int bsl = (kk * 4 + (lane >> 4)) ^ (br & 7);
                half8 bf = *(const half8*)&Bs[br * 64 + bsl * 8];
                acc[ni] = __builtin_amdgcn_mfma_f32_16x16x32_f16(af, bf, acc[ni], 0, 0, 0);
            }
        }
    }
    #pragma unroll
    for (int ni = 0; ni < 3; ni++) {
        #pragma unroll
        for (int q = 0; q < 4; q++) {
            int row = bm + w * 16 + (lane >> 4) * 4 + q;
            int col = ni * 16 + (lane & 15);
            pb[((size_t)kz * NROWS + row) * 48 + col] = acc[ni][q];
        }
    }
}

// ---------------- GEMM2 reduce: sum 8 partials, softplus col0, split B/C ----------------
__global__ __launch_bounds__(256)
void gemm2_reduce(const float* __restrict__ pb, float* __restrict__ delta,
                  float* __restrict__ Bm, float* __restrict__ Cm)
{
    int idx = blockIdx.x * 256 + threadIdx.x;      // 4096*48
    int row = idx / 48, col = idx - row * 48;
    float s = 0.f;
    #pragma unroll
    for (int kz = 0; kz < 8; kz++) s += pb[(size_t)kz * NROWS * 48 + idx];
    if (col == 0)       delta[row] = fmaxf(s, 0.f) + log1pf(__expf(-fabsf(s)));
    else if (col < 17)  Bm[row * NST + col - 1]  = s;
    else if (col < 33)  Cm[row * NST + col - 17] = s;
}

// ---------------- scan pass 1: thread-per-d, h[16] in regs; h -> f16, S per chunk ----
__global__ __launch_bounds__(256)
void scan_part1_reg(const u16* __restrict__ xc16, const float* __restrict__ delta,
                    const float* __restrict__ Bm, const float* __restrict__ A_log,
                    u16* __restrict__ h16, float* __restrict__ Sc)
{
    const int b = blockIdx.z, c = blockIdx.y;
    const int d = blockIdx.x * 256 + threadIdx.x;
    float ka[16];
    {
        const float4* Av = (const float4*)(A_log + (size_t)d * 16);
        #pragma unroll
        for (int q = 0; q < 4; q++) {
            float4 a = Av[q];
            ka[q*4+0] = -__expf(a.x) * 1.44269504f;
            ka[q*4+1] = -__expf(a.y) * 1.44269504f;
            ka[q*4+2] = -__expf(a.z) * 1.44269504f;
            ka[q*4+3] = -__expf(a.w) * 1.44269504f;
        }
    }
    float h[16];
    #pragma unroll
    for (int n = 0; n < 16; n++) h[n] = 0.f;
    float S = 0.f;
    const int rowbase = b * L_SEQ + c * CL;
    #pragma unroll 2
    for (int t = 0; t < CL; ++t) {
        const int rowg = rowbase + t;
        const float dt = delta[rowg];
        const float4* Bv = (const float4*)(Bm + (size_t)rowg * 16);
        float4 b0 = Bv[0], b1 = Bv[1], b2 = Bv[2], b3 = Bv[3];
        float bb[16] = {b0.x,b0.y,b0.z,b0.w, b1.x,b1.y,b1.z,b1.w,
                        b2.x,b2.y,b2.z,b2.w, b3.x,b3.y,b3.z,b3.w};
        const float xt = h2f(xc16[(size_t)rowg * DIN + d]);
        const float dtx = dt * xt;
        S += dt;
        #pragma unroll
        for (int n = 0; n < 16; n++) {
            float a = fexp2(dt * ka[n]);
            h[n] = fmaf(a, h[n], bb[n] * dtx);
        }
    }
    u16* hp = h16 + (((size_t)(b * NC + c) * DIN) + d) * 16;
    short8 o0, o1;
    #pragma unroll
    for (int j = 0; j < 8; j++) { o0[j] = (short)f2h_bits(h[j]); o1[j] = (short)f2h_bits(h[8 + j]); }
    *(short8*)&hp[0] = o0;
    *(short8*)&hp[8] = o1;
    if (threadIdx.x == 0 && blockIdx.x == 0) Sc[b * NC + c] = S;
}

// ---------------- scan pass 2: sequential carry across chunks (Pc recomputed) ----------
__global__ __launch_bounds__(256)
void scan_carry(const u16* __restrict__ h16, const float* __restrict__ Sc,
                const float* __restrict__ A_log, u16* __restrict__ H16)
{
    int gid = blockIdx.x * 256 + threadIdx.x;      // NB*DIN*NST = 65536
    int b = gid >> 15, r = gid & 32767;            // r = d*16 + n
    const float ka = -__expf(A_log[r]) * 1.44269504f;
    float H = 0.f;
    for (int c = 0; c < NC; ++c) {
        size_t idx = ((size_t)(b * NC + c) << 15) + r;
        H16[idx] = f2h_bits(H);
        float P = fexp2(Sc[b * NC + c] * ka);
        H = fmaf(P, H, h2f(h16[idx]));
    }
}

// ---------------- scan pass 3: thread-per-d, fused epilogue -> y fp16 ----------------
__global__ __launch_bounds__(256)
void scan_part3_reg(const u16* __restrict__ xc16, const float* __restrict__ delta,
                    const float* __restrict__ Bm, const float* __restrict__ Cm,
                    const float* __restrict__ A_log, const float* __restrict__ Dp,
                    const u16* __restrict__ res16, const u16* __restrict__ H16,
                    u16* __restrict__ yh)
{
    const int b = blockIdx.z, c = blockIdx.y;
    const int d = blockIdx.x * 256 + threadIdx.x;
    float ka[16];
    {
        const float4* Av = (const float4*)(A_log + (size_t)d * 16);
        #pragma unroll
        for (int q = 0; q < 4; q++) {
            float4 a = Av[q];
            ka[q*4+0] = -__expf(a.x) * 1.44269504f;
            ka[q*4+1] = -__expf(a.y) * 1.44269504f;
            ka[q*4+2] = -__expf(a.z) * 1.44269504f;
            ka[q*4+3] = -__expf(a.w) * 1.44269504f;
        }
    }
    float h[16];
    {
        const u16* Hp = H16 + (((size_t)(b * NC + c) * DIN) + d) * 16;
        short8 v0 = *(const short8*)&Hp[0];
        short8 v1 = *(const short8*)&Hp[8];
        #pragma unroll
        for (int j = 0; j < 8; j++) { h[j] = h2f((u16)v0[j]); h[8 + j] = h2f((u16)v1[j]); }
    }
    const float Dpd = Dp[d];
    const int rowbase = b * L_SEQ + c * CL;
    #pragma unroll 2
    for (int t = 0; t < CL; ++t) {
        const int rowg = rowbase + t;
        const float dt = delta[rowg];
        const float4* Bv = (const float4*)(Bm + (size_t)rowg * 16);
        const float4* Cv = (const float4*)(Cm + (size_t)rowg * 16);
        float4 b0 = Bv[0], b1 = Bv[1], b2 = Bv[2], b3 = Bv[3];
        float4 c0 = Cv[0], c1 = Cv[1], c2 = Cv[2], c3 = Cv[3];
        float bb[16] = {b0.x,b0.y,b0.z,b0.w, b1.x,b1.y,b1.z,b1.w,
                        b2.x,b2.y,b2.z,b2.w, b3.x,b3.y,b3.z,b3.w};
        float cc[16] = {c0.x,c0.y,c0.z,c0.w, c1.x,c1.y,c1.z,c1.w,
                        c2.x,c2.y,c2.z,c2.w, c3.x,c3.y,c3.z,c3.w};
        const float xt = h2f(xc16[(size_t)rowg * DIN + d]);
        const float rt = h2f(res16[(size_t)rowg * DIN + d]);
        const float dtx = dt * xt;
        float y = 0.f;
        #pragma unroll
        for (int n = 0; n < 16; n++) {
            float a = fexp2(dt * ka[n]);
            h[n] = fmaf(a, h[n], bb[n] * dtx);
            y = fmaf(cc[n], h[n], y);
        }
        y = (y + xt * Dpd) * rt;
        yh[(size_t)rowg * DIN + d] = f2h_bits(y);
    }
}

extern "C" void kernel_launch(void* const* d_in, const int* in_sizes, int n_in,
                              void* d_out, int out_size, void* d_ws, size_t ws_size,
                              hipStream_t stream)
{
    const float* x     = (const float*)d_in[0];
    const float* W_in  = (const float*)d_in[1];
    const float* cw    = (const float*)d_in[2];
    const float* cb    = (const float*)d_in[3];
    const float* Wx    = (const float*)d_in[4];
    const float* A_log = (const float*)d_in[5];
    const float* Dp    = (const float*)d_in[6];
    const float* W_out = (const float*)d_in[7];
    float* out = (float*)d_out;
    float* ws  = (float*)d_ws;

    // workspace (float slot offsets); aliases valid by stream-order lifetimes
    u16*   xin16 = (u16*)(ws);                     // [4096][2048] ; dead after conv
    u16*   y16   = (u16*)(ws);                     // alias
    u16*   res16 = (u16*)(ws + 4194304);           // [4096][2048]
    u16*   xc16  = (u16*)(ws + 8388608);           // [4096][2048]
    u16*   x16   = (u16*)(ws + 12582912);          // [4096][1024] ; dead after GEMM1
    u16*   p2    = (u16*)(ws + 12582912);          // [2][4096][1024] (alias x16+Bt1)
    u16*   Bt1   = (u16*)(ws + 14680064);          // [4096][1024] ; dead after GEMM1
    float* pb    = ws + 14680064;                  // [8][4096][48] f32 (dead before GEMM3)
    u16*   WxT16 = (u16*)(ws + 20971520);          // [48][2048]
    float* delta = ws + 21020672;                  // 4096
    float* Bm    = ws + 21024768;                  // 65536
    float* Cm    = ws + 21090304;                  // 65536
    float* Sc    = ws + 21155840;                  // 64 (padded to 1024)
    u16*   h16   = (u16*)(ws + 21156864);          // [NB*NC][DIN][16] u16 = 1048576 fl
    u16*   H16   = (u16*)(ws + 22205440);          // same size
    u16*   Bt3   = (u16*)(ws + 23254016);          // [1024][2048] (end 24302592 fl = 97 MB)

    dim3 blk(256), blk512(512);

    // 1) fused preprocessing
    prep_inputs<<<dim3(6016), blk, 0, stream>>>(x, W_in, W_out, Wx, x16, Bt1, Bt3, WxT16);
    // 2) GEMM1 (2-phase 256^2, hazard-minimal barriers): xin16 | silu(res)16
    gemm8b<1><<<dim3(16, 16, 1), blk512, 0, stream>>>(x16, Bt1, xin16, res16,
                                                      NROWS, 2 * DIN, DMOD, DMOD, DMOD);
    // 3) conv + bias + silu (LDS-tiled)
    conv_silu16t<<<dim3(DIN / 128, L_SEQ / 32, NB), blk, 0, stream>>>(xin16, cw, cb, xc16);
    // 4) ssm params
    gemm2_mfma<<<dim3(NROWS / 64, 8), blk, 0, stream>>>(xc16, WxT16, pb);
    gemm2_reduce<<<dim3(NROWS * 48 / 256), blk, 0, stream>>>(pb, delta, Bm, Cm);
    // 5) chunk-parallel scan (h/H fp16, Pc recomputed from S)
    scan_part1_reg<<<dim3(DIN / 256, NC, NB), blk, 0, stream>>>(xc16, delta, Bm, A_log, h16, Sc);
    scan_carry<<<dim3(NB * DIN * NST / 256), blk, 0, stream>>>(h16, Sc, A_log, H16);
    scan_part3_reg<<<dim3(DIN / 256, NC, NB), blk, 0, stream>>>(xc16, delta, Bm, Cm, A_log, Dp, res16, H16, y16);
    // 6) GEMM3 (gemm128c, split-K=2): grid (8,32,2) = 512 blocks, 2/CU, counted vmcnt(8)
    gemm128c<<<dim3(DMOD / 128, NROWS / 128, 2), blk, 0, stream>>>(y16, Bt3, p2,
                                                                   NROWS, DMOD, DIN / 2, DIN, DIN);
    // 7) out = p[0] + p[1] (fp32)
    add_partials<<<dim3(NROWS * DMOD / 8 / 256), blk, 0, stream>>>(p2, out);
}